// Round 7
// baseline (326.857 us; speedup 1.0000x reference)
//
#include <hip/hip_runtime.h>
#include <hip/hip_bf16.h>
#include <math.h>

#define BATCH 128
#define LSEQ 24
#define NN 121      // nodes == d_model == out feature
#define SSZ 64      // state size
#define NSTEPS 6
#define BL 3072     // BATCH*LSEQ

typedef _Float16 h16;
typedef _Float16 h16x2 __attribute__((ext_vector_type(2)));

// ---------------- kernel 1: encoder -> feat[121] (unchanged, verified) ----------------
__global__ __launch_bounds__(256) void enc_kernel(
    const float* __restrict__ x, const float* __restrict__ conv_w,
    const float* __restrict__ conv_b, const float* __restrict__ comp_w1,
    const float* __restrict__ comp_b1, const float* __restrict__ comp_w2,
    const float* __restrict__ comp_b2, float* __restrict__ feat_out)
{
    const int n = blockIdx.x;     // node
    const int tid = threadIdx.x;
    float acc[8] = {0.f,0.f,0.f,0.f,0.f,0.f,0.f,0.f};
    for (int i = tid; i < BL; i += 256) {
        const float xv = x[i * NN + n];
        const float4* w4 = reinterpret_cast<const float4*>(conv_w + i * 8);
        const float4 a = w4[0], b = w4[1];
        acc[0] += xv * a.x; acc[1] += xv * a.y; acc[2] += xv * a.z; acc[3] += xv * a.w;
        acc[4] += xv * b.x; acc[5] += xv * b.y; acc[6] += xv * b.z; acc[7] += xv * b.w;
    }
    __shared__ float red[256][9];   // pad 9: conflict-free
    __shared__ float hred[32];
    #pragma unroll
    for (int j = 0; j < 8; ++j) red[tid][j] = acc[j];
    __syncthreads();
    for (int s = 128; s > 0; s >>= 1) {
        if (tid < s) {
            #pragma unroll
            for (int j = 0; j < 8; ++j) red[tid][j] += red[tid + s][j];
        }
        __syncthreads();
    }
    if (tid < 32) {
        float g[8];
        #pragma unroll
        for (int j = 0; j < 8; ++j) g[j] = red[0][j] + conv_b[j];
        float hsum = comp_b1[tid];
        #pragma unroll
        for (int j = 0; j < 8; ++j)
            hsum += g[j] * (comp_w1[j * 32 + tid] + comp_w1[(j + 8) * 32 + tid]);
        const float hv = hsum > 0.f ? hsum : 0.01f * hsum;   // leaky
        hred[tid] = hv * comp_w2[tid];
    }
    __syncthreads();
    if (tid == 0) {
        float f = comp_b2[0];
        #pragma unroll
        for (int m = 0; m < 32; ++m) f += hred[m];
        feat_out[n] = f;
    }
}

// ---------------- kernel 2: sequential mamba chain (1 block, reg-resident weights) ----------------
__device__ __forceinline__ float softplus_f(float v) {
    return v > 20.f ? v : log1pf(expf(v));
}

// classic streaming matvec (used once, for adapter)
template<int ROWS, int COLS, int ACT>
__device__ __forceinline__ void matvec4(
    const float* __restrict__ W, const float* __restrict__ bias,
    const float* in, float* out, float* red, int tid)
{
    const int slice = tid >> 7;       // 0..3
    const int j = tid & 127;
    float a0 = 0.f, a1 = 0.f, a2 = 0.f, a3 = 0.f;
    if (j < COLS) {
        const int r0 = (ROWS * slice) >> 2;
        const int r1 = (ROWS * (slice + 1)) >> 2;
        int i = r0;
        #pragma unroll 2
        for (; i + 4 <= r1; i += 4) {
            a0 += in[i + 0] * W[(i + 0) * COLS + j];
            a1 += in[i + 1] * W[(i + 1) * COLS + j];
            a2 += in[i + 2] * W[(i + 2) * COLS + j];
            a3 += in[i + 3] * W[(i + 3) * COLS + j];
        }
        for (; i < r1; ++i) a0 += in[i] * W[i * COLS + j];
    }
    red[tid] = (a0 + a1) + (a2 + a3);
    __syncthreads();
    if (tid < COLS) {
        float s = red[tid] + red[tid + 128] + red[tid + 256] + red[tid + 384] + bias[tid];
        if (ACT == 1) s = fmaxf(s, 0.f);
        else if (ACT == 2) s = tanhf(s);
        out[tid] = s;
    }
    __syncthreads();
}

// preload per-thread fp16 weight slice, identity row map, rows >= R -> 0, j >= COLS -> 0
template<int PADR, int R, int COLS>
__device__ __forceinline__ void load_w_id(const float* __restrict__ W, h16x2* w, int tid)
{
    const int slice = tid >> 7, j = tid & 127;
    const int r0 = (PADR / 4) * slice;
    const bool jv = (j < COLS);
    #pragma unroll
    for (int m = 0; m < PADR / 8; ++m) {
        const int rp0 = r0 + 2 * m, rp1 = rp0 + 1;
        const float w0 = (jv && rp0 < R) ? W[rp0 * COLS + j] : 0.f;
        const float w1 = (jv && rp1 < R) ? W[rp1 * COLS + j] : 0.f;
        h16x2 p; p.x = (h16)w0; p.y = (h16)w1;
        w[m] = p;
    }
}

// reg-weight matvec: in = LDS fp32 vector padded to PADR (16B aligned, pads zero)
template<int PADR, int COLS, int ACT>
__device__ __forceinline__ void matvec_reg(
    const h16x2* w, const float* __restrict__ biasLds,
    const float* in, float* out, float* red, int tid)
{
    const int slice = tid >> 7;
    const float4* in4 = reinterpret_cast<const float4*>(in + (PADR / 4) * slice);
    float acc0 = 0.f, acc1 = 0.f;
    #pragma unroll
    for (int m = 0; m < PADR / 16; ++m) {
        const float4 q = in4[m];
        const h16x2 a = w[2 * m], b = w[2 * m + 1];
        acc0 += q.x * (float)a.x + q.y * (float)a.y;
        acc1 += q.z * (float)b.x + q.w * (float)b.y;
    }
    red[tid] = acc0 + acc1;
    __syncthreads();
    if (tid < COLS) {
        float s = red[tid] + red[tid + 128] + red[tid + 256] + red[tid + 384] + biasLds[tid];
        if (ACT == 1) s = fmaxf(s, 0.f);
        else if (ACT == 2) s = tanhf(s);
        out[tid] = s;
    }
    __syncthreads();
}

__global__ __launch_bounds__(512) void mamba_kernel(
    const float* __restrict__ adapter_w, const float* __restrict__ adapter_b,
    const float* __restrict__ ln_g, const float* __restrict__ ln_b,
    const float* __restrict__ lift_w1, const float* __restrict__ lift_b1,
    const float* __restrict__ lift_w2, const float* __restrict__ lift_b2,
    const float* __restrict__ net_w1, const float* __restrict__ net_b1,
    const float* __restrict__ net_w2, const float* __restrict__ net_b2,
    const float* __restrict__ fc1_w, const float* __restrict__ fc1_b,
    const float* __restrict__ fc2_w, const float* __restrict__ fc2_b,
    const float* __restrict__ fc3_w, const float* __restrict__ fc3_b,
    const float* __restrict__ Aw, const float* __restrict__ state_init,
    const float* __restrict__ fcout_w, const float* __restrict__ fcout_b,
    const float* __restrict__ feat_in, float* __restrict__ pred_out)
{
    __shared__ __align__(16) float catP[256];   // q [0,121)+pad0, lifted [128,249)+pad0
    __shared__ __align__(16) float t1[128], t2[128], xtsP[128];
    __shared__ __align__(16) float outvP[128];
    __shared__ float deltas[128], Bms[64], Cms[64], zb[128], ftmp[128];
    __shared__ float red[512], redb[512];
    __shared__ float lb1[128], lb2[128], nb1[128], nb2[128];
    __shared__ float f1b[128], f2b[64], f3b[64], fob[128];
    __shared__ float scal[2];

    const int tid = threadIdx.x;

    // ---- per-thread register-resident fp16 weights (loaded once) ----
    h16x2 wl1[16], wl2[16], wn1[32], wn2[16], wf[32], wo[16];
    load_w_id<128, 121, 128>(lift_w1, wl1, tid);
    load_w_id<128, 128, 121>(lift_w2, wl2, tid);
    load_w_id<128, 128, 121>(net_w2, wn2, tid);
    load_w_id<128, 121, 121>(fcout_w, wo, tid);
    {   // net_w1: orig rows 0..241 -> padded 0..120, gap, 128..248
        const int slice = tid >> 7, j = tid & 127;
        const int r0 = 64 * slice;
        #pragma unroll
        for (int m = 0; m < 32; ++m) {
            const int rp0 = r0 + 2 * m, rp1 = rp0 + 1;
            const int o0 = rp0 < 121 ? rp0 : (rp0 >= 128 && rp0 < 249 ? rp0 - 7 : -1);
            const int o1 = rp1 < 121 ? rp1 : (rp1 >= 128 && rp1 < 249 ? rp1 - 7 : -1);
            const float w0 = (o0 >= 0) ? net_w1[o0 * 128 + j] : 0.f;
            const float w1 = (o1 >= 0) ? net_w1[o1 * 128 + j] : 0.f;
            h16x2 p; p.x = (h16)w0; p.y = (h16)w1;
            wn1[m] = p;
        }
    }
    {   // fused fc1/fc2/fc3: 2 slices x 256 threads, 64 padded rows each
        const int slice = tid >> 8, j = tid & 255;
        const float* Wp = nullptr; int col = 0, C = 0;
        if (j < 121)                  { Wp = fc1_w; col = j;       C = 121; }
        else if (j >= 128 && j < 192) { Wp = fc2_w; col = j - 128; C = 64; }
        else if (j >= 192)            { Wp = fc3_w; col = j - 192; C = 64; }
        const int r0 = 64 * slice;
        #pragma unroll
        for (int m = 0; m < 32; ++m) {
            const int rp0 = r0 + 2 * m, rp1 = rp0 + 1;
            const float w0 = (Wp && rp0 < 121) ? Wp[rp0 * C + col] : 0.f;
            const float w1 = (Wp && rp1 < 121) ? Wp[rp1 * C + col] : 0.f;
            h16x2 p; p.x = (h16)w0; p.y = (h16)w1;
            wf[m] = p;
        }
    }

    // ---- per-thread register h / A (chunked (c,d) as in h-update) ----
    const int hc = tid >> 7, hd = tid & 127;
    float Areg[16], hreg[16];
    #pragma unroll
    for (int k = 0; k < 16; ++k) { Areg[k] = 0.f; hreg[k] = 0.f; }
    if (hd < NN) {
        #pragma unroll
        for (int k = 0; k < 16; ++k) {
            Areg[k] = Aw[hd * SSZ + hc * 16 + k];
            hreg[k] = state_init[hd * SSZ + hc * 16 + k];
        }
    }

    // ---- biases to LDS, zero pads, feat ----
    if (tid < 128) { lb1[tid] = lift_b1[tid]; nb1[tid] = net_b1[tid]; }
    if (tid < 121) {
        lb2[tid] = lift_b2[tid]; nb2[tid] = net_b2[tid];
        f1b[tid] = fc1_b[tid];   fob[tid] = fcout_b[tid];
        ftmp[tid] = feat_in[tid];
    }
    if (tid < 64) { f2b[tid] = fc2_b[tid]; f3b[tid] = fc3_b[tid]; }
    if (tid >= 121 && tid < 128) { catP[tid] = 0.f; xtsP[tid] = 0.f; outvP[tid] = 0.f; }
    if (tid >= 249 && tid < 256) catP[tid] = 0.f;
    __syncthreads();

    // z = feat @ adapter_w + adapter_b (streamed, once)
    matvec4<NN, NN, 0>(adapter_w, adapter_b, ftmp, zb, red, tid);

    // layernorm -> q (catP[0..121))
    {
        const float v = (tid < NN) ? zb[tid] : 0.f;
        red[tid] = v; redb[tid] = v * v;
        __syncthreads();
        for (int s = 256; s > 0; s >>= 1) {
            if (tid < s) { red[tid] += red[tid + s]; redb[tid] += redb[tid + s]; }
            __syncthreads();
        }
        if (tid == 0) {
            const float mu = red[0] / (float)NN;
            const float var = redb[0] / (float)NN - mu * mu;
            scal[0] = mu; scal[1] = 1.0f / sqrtf(var + 1e-5f);
        }
        __syncthreads();
        if (tid < NN) catP[tid] = (zb[tid] - scal[0]) * scal[1] * ln_g[tid] + ln_b[tid];
        __syncthreads();
    }

    // ev 0 = warmup (h only), ev 1..6 = steps (produce pred, feed back)
    for (int ev = 0; ev < 7; ++ev) {
        matvec_reg<128, 128, 1>(wl1, lb1, catP, t1, red, tid);          // relu
        matvec_reg<128, 121, 2>(wl2, lb2, t1, catP + 128, red, tid);    // tanh -> lifted
        matvec_reg<256, 128, 1>(wn1, nb1, catP, t2, red, tid);          // relu
        matvec_reg<128, 121, 0>(wn2, nb2, t2, xtsP, red, tid);          // xt

        // fused delta / Bm / Cm (2 slices of 256 threads, reg weights)
        {
            const int slice = tid >> 8;
            const float4* in4 = reinterpret_cast<const float4*>(xtsP + 64 * slice);
            float acc0 = 0.f, acc1 = 0.f;
            #pragma unroll
            for (int m = 0; m < 16; ++m) {
                const float4 q = in4[m];
                const h16x2 a = wf[2 * m], b = wf[2 * m + 1];
                acc0 += q.x * (float)a.x + q.y * (float)a.y;
                acc1 += q.z * (float)b.x + q.w * (float)b.y;
            }
            red[tid] = acc0 + acc1;
            __syncthreads();
            if (tid < 121)
                deltas[tid] = softplus_f(red[tid] + red[tid + 256] + f1b[tid]);
            else if (tid >= 128 && tid < 192)
                Bms[tid - 128] = red[tid] + red[tid + 256] + f2b[tid - 128];
            else if (tid >= 192 && tid < 256)
                Cms[tid - 192] = red[tid] + red[tid + 256] + f3b[tid - 192];
            __syncthreads();
        }

        // h update (registers) + out[d] = sum_n Cm[n]*h_new[d,n]
        {
            float acc = 0.f;
            if (hd < NN) {
                const float dd = deltas[hd];
                const float coef = xtsP[hd] * dd;
                #pragma unroll
                for (int k = 0; k < 16; ++k) {
                    const float s = dd * Areg[k];
                    const float cel = s > 0.f ? s : expm1f(s);   // celu, alpha=1
                    const float dAv = expf(-cel);
                    const float hn = dAv * hreg[k] + coef * Bms[hc * 16 + k];
                    hreg[k] = hn;
                    acc += Cms[hc * 16 + k] * hn;
                }
            }
            red[tid] = acc;
            __syncthreads();
            if (tid < NN) outvP[tid] = red[tid] + red[tid + 128] + red[tid + 256] + red[tid + 384];
            __syncthreads();
        }

        if (ev > 0) {
            matvec_reg<128, 121, 0>(wo, fob, outvP, catP, red, tid);    // pred -> q
            if (tid < NN) pred_out[(ev - 1) * NN + tid] = catP[tid];
            __syncthreads();
        }
    }
}

// ---------------- kernel 3: broadcast preds to (steps,b,l,m) ----------------
__global__ __launch_bounds__(128) void bcast_kernel(
    const float* __restrict__ pred, float* __restrict__ out)
{
    const int row = blockIdx.x;            // s*3072 + (b*24+l), 18432 rows
    const int s = row / BL;
    const int t = threadIdx.x;
    if (t < NN) out[row * NN + t] = pred[s * NN + t];
}

extern "C" void kernel_launch(void* const* d_in, const int* in_sizes, int n_in,
                              void* d_out, int out_size, void* d_ws, size_t ws_size,
                              hipStream_t stream)
{
    const float* x        = (const float*)d_in[0];
    const float* conv_w   = (const float*)d_in[3];
    const float* conv_b   = (const float*)d_in[4];
    const float* comp_w1  = (const float*)d_in[5];
    const float* comp_b1  = (const float*)d_in[6];
    const float* comp_w2  = (const float*)d_in[7];
    const float* comp_b2  = (const float*)d_in[8];
    const float* adapter_w= (const float*)d_in[9];
    const float* adapter_b= (const float*)d_in[10];
    const float* ln_g     = (const float*)d_in[11];
    const float* ln_b     = (const float*)d_in[12];
    const float* lift_w1  = (const float*)d_in[13];
    const float* lift_b1  = (const float*)d_in[14];
    const float* lift_w2  = (const float*)d_in[15];
    const float* lift_b2  = (const float*)d_in[16];
    const float* net_w1   = (const float*)d_in[17];
    const float* net_b1   = (const float*)d_in[18];
    const float* net_w2   = (const float*)d_in[19];
    const float* net_b2   = (const float*)d_in[20];
    const float* fc1_w    = (const float*)d_in[21];
    const float* fc1_b    = (const float*)d_in[22];
    const float* fc2_w    = (const float*)d_in[23];
    const float* fc2_b    = (const float*)d_in[24];
    const float* fc3_w    = (const float*)d_in[25];
    const float* fc3_b    = (const float*)d_in[26];
    const float* Aw       = (const float*)d_in[27];
    const float* state_in = (const float*)d_in[28];
    const float* fcout_w  = (const float*)d_in[29];
    const float* fcout_b  = (const float*)d_in[30];

    float* ws   = (float*)d_ws;
    float* feat = ws;          // 121 floats
    float* pred = ws + 128;    // 6*121 floats

    enc_kernel<<<NN, 256, 0, stream>>>(x, conv_w, conv_b, comp_w1, comp_b1,
                                       comp_w2, comp_b2, feat);
    mamba_kernel<<<1, 512, 0, stream>>>(adapter_w, adapter_b, ln_g, ln_b,
        lift_w1, lift_b1, lift_w2, lift_b2, net_w1, net_b1, net_w2, net_b2,
        fc1_w, fc1_b, fc2_w, fc2_b, fc3_w, fc3_b, Aw, state_in,
        fcout_w, fcout_b, feat, pred);
    bcast_kernel<<<NSTEPS * BL, 128, 0, stream>>>(pred, (float*)d_out);
}

// Round 10
// 323.900 us; speedup vs baseline: 1.0091x; 1.0091x over previous
//
#include <hip/hip_runtime.h>
#include <hip/hip_bf16.h>
#include <math.h>

#define BATCH 128
#define LSEQ 24
#define NN 121      // nodes == d_model == out feature
#define SSZ 64      // state size
#define NSTEPS 6
#define BL 3072     // BATCH*LSEQ

typedef _Float16 h16;
typedef _Float16 h16x2 __attribute__((ext_vector_type(2)));

// ---------------- kernel 1: encoder -> feat[121] (unchanged, verified) ----------------
__global__ __launch_bounds__(256) void enc_kernel(
    const float* __restrict__ x, const float* __restrict__ conv_w,
    const float* __restrict__ conv_b, const float* __restrict__ comp_w1,
    const float* __restrict__ comp_b1, const float* __restrict__ comp_w2,
    const float* __restrict__ comp_b2, float* __restrict__ feat_out)
{
    const int n = blockIdx.x;     // node
    const int tid = threadIdx.x;
    float acc[8] = {0.f,0.f,0.f,0.f,0.f,0.f,0.f,0.f};
    for (int i = tid; i < BL; i += 256) {
        const float xv = x[i * NN + n];
        const float4* w4 = reinterpret_cast<const float4*>(conv_w + i * 8);
        const float4 a = w4[0], b = w4[1];
        acc[0] += xv * a.x; acc[1] += xv * a.y; acc[2] += xv * a.z; acc[3] += xv * a.w;
        acc[4] += xv * b.x; acc[5] += xv * b.y; acc[6] += xv * b.z; acc[7] += xv * b.w;
    }
    __shared__ float red[256][9];   // pad 9: conflict-free
    __shared__ float hred[32];
    #pragma unroll
    for (int j = 0; j < 8; ++j) red[tid][j] = acc[j];
    __syncthreads();
    for (int s = 128; s > 0; s >>= 1) {
        if (tid < s) {
            #pragma unroll
            for (int j = 0; j < 8; ++j) red[tid][j] += red[tid + s][j];
        }
        __syncthreads();
    }
    if (tid < 32) {
        float g[8];
        #pragma unroll
        for (int j = 0; j < 8; ++j) g[j] = red[0][j] + conv_b[j];
        float hsum = comp_b1[tid];
        #pragma unroll
        for (int j = 0; j < 8; ++j)
            hsum += g[j] * (comp_w1[j * 32 + tid] + comp_w1[(j + 8) * 32 + tid]);
        const float hv = hsum > 0.f ? hsum : 0.01f * hsum;   // leaky
        hred[tid] = hv * comp_w2[tid];
    }
    __syncthreads();
    if (tid == 0) {
        float f = comp_b2[0];
        #pragma unroll
        for (int m = 0; m < 32; ++m) f += hred[m];
        feat_out[n] = f;
    }
}

// ---------------- kernel 2: sequential mamba chain (1 block, reg-resident weights) ----------------
__device__ __forceinline__ float softplus_f(float v) {
    return v > 20.f ? v : log1pf(expf(v));
}

// classic streaming matvec (used once, for adapter)
template<int ROWS, int COLS, int ACT>
__device__ __forceinline__ void matvec4(
    const float* __restrict__ W, const float* __restrict__ bias,
    const float* in, float* out, float* red, int tid)
{
    const int slice = tid >> 7;       // 0..3
    const int j = tid & 127;
    float a0 = 0.f, a1 = 0.f, a2 = 0.f, a3 = 0.f;
    if (j < COLS) {
        const int r0 = (ROWS * slice) >> 2;
        const int r1 = (ROWS * (slice + 1)) >> 2;
        int i = r0;
        #pragma unroll 2
        for (; i + 4 <= r1; i += 4) {
            a0 += in[i + 0] * W[(i + 0) * COLS + j];
            a1 += in[i + 1] * W[(i + 1) * COLS + j];
            a2 += in[i + 2] * W[(i + 2) * COLS + j];
            a3 += in[i + 3] * W[(i + 3) * COLS + j];
        }
        for (; i < r1; ++i) a0 += in[i] * W[i * COLS + j];
    }
    red[tid] = (a0 + a1) + (a2 + a3);
    __syncthreads();
    if (tid < COLS) {
        float s = red[tid] + red[tid + 128] + red[tid + 256] + red[tid + 384] + bias[tid];
        if (ACT == 1) s = fmaxf(s, 0.f);
        else if (ACT == 2) s = tanhf(s);
        out[tid] = s;
    }
    __syncthreads();
}

// preload per-thread fp16 weight slice, identity row map, rows >= R -> 0, j >= COLS -> 0
template<int PADR, int R, int COLS>
__device__ __forceinline__ void load_w_id(const float* __restrict__ W, h16x2* w, int tid)
{
    const int slice = tid >> 7, j = tid & 127;
    const int r0 = (PADR / 4) * slice;
    const bool jv = (j < COLS);
    #pragma unroll
    for (int m = 0; m < PADR / 8; ++m) {
        const int rp0 = r0 + 2 * m, rp1 = rp0 + 1;
        const float w0 = (jv && rp0 < R) ? W[rp0 * COLS + j] : 0.f;
        const float w1 = (jv && rp1 < R) ? W[rp1 * COLS + j] : 0.f;
        h16x2 p; p.x = (h16)w0; p.y = (h16)w1;
        w[m] = p;
    }
}

// reg-weight matvec: in = LDS fp32 vector padded to PADR (16B aligned, pads zero)
template<int PADR, int COLS, int ACT>
__device__ __forceinline__ void matvec_reg(
    const h16x2* w, const float* __restrict__ biasLds,
    const float* in, float* out, float* red, int tid)
{
    const int slice = tid >> 7;
    const float4* in4 = reinterpret_cast<const float4*>(in + (PADR / 4) * slice);
    float acc0 = 0.f, acc1 = 0.f;
    #pragma unroll
    for (int m = 0; m < PADR / 16; ++m) {
        const float4 q = in4[m];
        const h16x2 a = w[2 * m], b = w[2 * m + 1];
        acc0 += q.x * (float)a.x + q.y * (float)a.y;
        acc1 += q.z * (float)b.x + q.w * (float)b.y;
    }
    red[tid] = acc0 + acc1;
    __syncthreads();
    if (tid < COLS) {
        float s = red[tid] + red[tid + 128] + red[tid + 256] + red[tid + 384] + biasLds[tid];
        if (ACT == 1) s = fmaxf(s, 0.f);
        else if (ACT == 2) s = tanhf(s);
        out[tid] = s;
    }
    __syncthreads();
}

// __launch_bounds__(512, 2): 8 waves/block = exactly 2 waves/SIMD -> VGPR cap 256,
// fits the ~200-VGPR weight-resident working set with NO scratch spills.
__global__ __launch_bounds__(512, 2) void mamba_kernel(
    const float* __restrict__ adapter_w, const float* __restrict__ adapter_b,
    const float* __restrict__ ln_g, const float* __restrict__ ln_b,
    const float* __restrict__ lift_w1, const float* __restrict__ lift_b1,
    const float* __restrict__ lift_w2, const float* __restrict__ lift_b2,
    const float* __restrict__ net_w1, const float* __restrict__ net_b1,
    const float* __restrict__ net_w2, const float* __restrict__ net_b2,
    const float* __restrict__ fc1_w, const float* __restrict__ fc1_b,
    const float* __restrict__ fc2_w, const float* __restrict__ fc2_b,
    const float* __restrict__ fc3_w, const float* __restrict__ fc3_b,
    const float* __restrict__ Aw, const float* __restrict__ state_init,
    const float* __restrict__ fcout_w, const float* __restrict__ fcout_b,
    const float* __restrict__ feat_in, float* __restrict__ pred_out)
{
    __shared__ __align__(16) float catP[256];   // q [0,121)+pad0, lifted [128,249)+pad0
    __shared__ __align__(16) float t1[128], t2[128], xtsP[128];
    __shared__ __align__(16) float outvP[128];
    __shared__ float deltas[128], Bms[64], Cms[64], zb[128], ftmp[128];
    __shared__ float red[512], redb[512];
    __shared__ float lb1[128], lb2[128], nb1[128], nb2[128];
    __shared__ float f1b[128], f2b[64], f3b[64], fob[128];
    __shared__ float scal[2];

    const int tid = threadIdx.x;

    // ---- per-thread register-resident fp16 weights (loaded once) ----
    h16x2 wl1[16], wl2[16], wn1[32], wn2[16], wf[32], wo[16];
    load_w_id<128, 121, 128>(lift_w1, wl1, tid);
    load_w_id<128, 128, 121>(lift_w2, wl2, tid);
    load_w_id<128, 128, 121>(net_w2, wn2, tid);
    load_w_id<128, 121, 121>(fcout_w, wo, tid);
    {   // net_w1: orig rows 0..241 -> padded 0..120, gap, 128..248
        const int slice = tid >> 7, j = tid & 127;
        const int r0 = 64 * slice;
        #pragma unroll
        for (int m = 0; m < 32; ++m) {
            const int rp0 = r0 + 2 * m, rp1 = rp0 + 1;
            const int o0 = rp0 < 121 ? rp0 : (rp0 >= 128 && rp0 < 249 ? rp0 - 7 : -1);
            const int o1 = rp1 < 121 ? rp1 : (rp1 >= 128 && rp1 < 249 ? rp1 - 7 : -1);
            const float w0 = (o0 >= 0) ? net_w1[o0 * 128 + j] : 0.f;
            const float w1 = (o1 >= 0) ? net_w1[o1 * 128 + j] : 0.f;
            h16x2 p; p.x = (h16)w0; p.y = (h16)w1;
            wn1[m] = p;
        }
    }
    {   // fused fc1/fc2/fc3: 2 slices x 256 threads, 64 padded rows each
        const int slice = tid >> 8, j = tid & 255;
        const float* Wp = nullptr; int col = 0, C = 0;
        if (j < 121)                  { Wp = fc1_w; col = j;       C = 121; }
        else if (j >= 128 && j < 192) { Wp = fc2_w; col = j - 128; C = 64; }
        else if (j >= 192)            { Wp = fc3_w; col = j - 192; C = 64; }
        const int r0 = 64 * slice;
        #pragma unroll
        for (int m = 0; m < 32; ++m) {
            const int rp0 = r0 + 2 * m, rp1 = rp0 + 1;
            const float w0 = (Wp && rp0 < 121) ? Wp[rp0 * C + col] : 0.f;
            const float w1 = (Wp && rp1 < 121) ? Wp[rp1 * C + col] : 0.f;
            h16x2 p; p.x = (h16)w0; p.y = (h16)w1;
            wf[m] = p;
        }
    }

    // ---- per-thread register h / A (chunked (c,d) as in h-update) ----
    const int hc = tid >> 7, hd = tid & 127;
    float Areg[16], hreg[16];
    #pragma unroll
    for (int k = 0; k < 16; ++k) { Areg[k] = 0.f; hreg[k] = 0.f; }
    if (hd < NN) {
        #pragma unroll
        for (int k = 0; k < 16; ++k) {
            Areg[k] = Aw[hd * SSZ + hc * 16 + k];
            hreg[k] = state_init[hd * SSZ + hc * 16 + k];
        }
    }

    // ---- biases to LDS, zero pads, feat ----
    if (tid < 128) { lb1[tid] = lift_b1[tid]; nb1[tid] = net_b1[tid]; }
    if (tid < 121) {
        lb2[tid] = lift_b2[tid]; nb2[tid] = net_b2[tid];
        f1b[tid] = fc1_b[tid];   fob[tid] = fcout_b[tid];
        ftmp[tid] = feat_in[tid];
    }
    if (tid < 64) { f2b[tid] = fc2_b[tid]; f3b[tid] = fc3_b[tid]; }
    if (tid >= 121 && tid < 128) { catP[tid] = 0.f; xtsP[tid] = 0.f; outvP[tid] = 0.f; }
    if (tid >= 249 && tid < 256) catP[tid] = 0.f;
    __syncthreads();

    // z = feat @ adapter_w + adapter_b (streamed, once)
    matvec4<NN, NN, 0>(adapter_w, adapter_b, ftmp, zb, red, tid);

    // layernorm -> q (catP[0..121))
    {
        const float v = (tid < NN) ? zb[tid] : 0.f;
        red[tid] = v; redb[tid] = v * v;
        __syncthreads();
        for (int s = 256; s > 0; s >>= 1) {
            if (tid < s) { red[tid] += red[tid + s]; redb[tid] += redb[tid + s]; }
            __syncthreads();
        }
        if (tid == 0) {
            const float mu = red[0] / (float)NN;
            const float var = redb[0] / (float)NN - mu * mu;
            scal[0] = mu; scal[1] = 1.0f / sqrtf(var + 1e-5f);
        }
        __syncthreads();
        if (tid < NN) catP[tid] = (zb[tid] - scal[0]) * scal[1] * ln_g[tid] + ln_b[tid];
        __syncthreads();
    }

    // ev 0 = warmup (h only), ev 1..6 = steps (produce pred, feed back)
    for (int ev = 0; ev < 7; ++ev) {
        matvec_reg<128, 128, 1>(wl1, lb1, catP, t1, red, tid);          // relu
        matvec_reg<128, 121, 2>(wl2, lb2, t1, catP + 128, red, tid);    // tanh -> lifted
        matvec_reg<256, 128, 1>(wn1, nb1, catP, t2, red, tid);          // relu
        matvec_reg<128, 121, 0>(wn2, nb2, t2, xtsP, red, tid);          // xt

        // fused delta / Bm / Cm (2 slices of 256 threads, reg weights)
        {
            const int slice = tid >> 8;
            const float4* in4 = reinterpret_cast<const float4*>(xtsP + 64 * slice);
            float acc0 = 0.f, acc1 = 0.f;
            #pragma unroll
            for (int m = 0; m < 16; ++m) {
                const float4 q = in4[m];
                const h16x2 a = wf[2 * m], b = wf[2 * m + 1];
                acc0 += q.x * (float)a.x + q.y * (float)a.y;
                acc1 += q.z * (float)b.x + q.w * (float)b.y;
            }
            red[tid] = acc0 + acc1;
            __syncthreads();
            if (tid < 121)
                deltas[tid] = softplus_f(red[tid] + red[tid + 256] + f1b[tid]);
            else if (tid >= 128 && tid < 192)
                Bms[tid - 128] = red[tid] + red[tid + 256] + f2b[tid - 128];
            else if (tid >= 192 && tid < 256)
                Cms[tid - 192] = red[tid] + red[tid + 256] + f3b[tid - 192];
            __syncthreads();
        }

        // h update (registers) + out[d] = sum_n Cm[n]*h_new[d,n]
        {
            float acc = 0.f;
            if (hd < NN) {
                const float dd = deltas[hd];
                const float coef = xtsP[hd] * dd;
                #pragma unroll
                for (int k = 0; k < 16; ++k) {
                    const float s = dd * Areg[k];
                    const float cel = s > 0.f ? s : expm1f(s);   // celu, alpha=1
                    const float dAv = expf(-cel);
                    const float hn = dAv * hreg[k] + coef * Bms[hc * 16 + k];
                    hreg[k] = hn;
                    acc += Cms[hc * 16 + k] * hn;
                }
            }
            red[tid] = acc;
            __syncthreads();
            if (tid < NN) outvP[tid] = red[tid] + red[tid + 128] + red[tid + 256] + red[tid + 384];
            __syncthreads();
        }

        if (ev > 0) {
            matvec_reg<128, 121, 0>(wo, fob, outvP, catP, red, tid);    // pred -> q
            if (tid < NN) pred_out[(ev - 1) * NN + tid] = catP[tid];
            __syncthreads();
        }
    }
}

// ---------------- kernel 3: broadcast preds to (steps,b,l,m) ----------------
__global__ __launch_bounds__(128) void bcast_kernel(
    const float* __restrict__ pred, float* __restrict__ out)
{
    const int row = blockIdx.x;            // s*3072 + (b*24+l), 18432 rows
    const int s = row / BL;
    const int t = threadIdx.x;
    if (t < NN) out[row * NN + t] = pred[s * NN + t];
}

extern "C" void kernel_launch(void* const* d_in, const int* in_sizes, int n_in,
                              void* d_out, int out_size, void* d_ws, size_t ws_size,
                              hipStream_t stream)
{
    const float* x        = (const float*)d_in[0];
    const float* conv_w   = (const float*)d_in[3];
    const float* conv_b   = (const float*)d_in[4];
    const float* comp_w1  = (const float*)d_in[5];
    const float* comp_b1  = (const float*)d_in[6];
    const float* comp_w2  = (const float*)d_in[7];
    const float* comp_b2  = (const float*)d_in[8];
    const float* adapter_w= (const float*)d_in[9];
    const float* adapter_b= (const float*)d_in[10];
    const float* ln_g     = (const float*)d_in[11];
    const float* ln_b     = (const float*)d_in[12];
    const float* lift_w1  = (const float*)d_in[13];
    const float* lift_b1  = (const float*)d_in[14];
    const float* lift_w2  = (const float*)d_in[15];
    const float* lift_b2  = (const float*)d_in[16];
    const float* net_w1   = (const float*)d_in[17];
    const float* net_b1   = (const float*)d_in[18];
    const float* net_w2   = (const float*)d_in[19];
    const float* net_b2   = (const float*)d_in[20];
    const float* fc1_w    = (const float*)d_in[21];
    const float* fc1_b    = (const float*)d_in[22];
    const float* fc2_w    = (const float*)d_in[23];
    const float* fc2_b    = (const float*)d_in[24];
    const float* fc3_w    = (const float*)d_in[25];
    const float* fc3_b    = (const float*)d_in[26];
    const float* Aw       = (const float*)d_in[27];
    const float* state_in = (const float*)d_in[28];
    const float* fcout_w  = (const float*)d_in[29];
    const float* fcout_b  = (const float*)d_in[30];

    float* ws   = (float*)d_ws;
    float* feat = ws;          // 121 floats
    float* pred = ws + 128;    // 6*121 floats

    enc_kernel<<<NN, 256, 0, stream>>>(x, conv_w, conv_b, comp_w1, comp_b1,
                                       comp_w2, comp_b2, feat);
    mamba_kernel<<<1, 512, 0, stream>>>(adapter_w, adapter_b, ln_g, ln_b,
        lift_w1, lift_b1, lift_w2, lift_b2, net_w1, net_b1, net_w2, net_b2,
        fc1_w, fc1_b, fc2_w, fc2_b, fc3_w, fc3_b, Aw, state_in,
        fcout_w, fcout_b, feat, pred);
    bcast_kernel<<<NSTEPS * BL, 128, 0, stream>>>(pred, (float*)d_out);
}

// Round 11
// 323.541 us; speedup vs baseline: 1.0103x; 1.0011x over previous
//
#include <hip/hip_runtime.h>
#include <hip/hip_bf16.h>
#include <math.h>

#define BATCH 128
#define LSEQ 24
#define NN 121      // nodes == d_model == out feature
#define SSZ 64      // state size
#define NSTEPS 6
#define BL 3072     // BATCH*LSEQ

typedef _Float16 h16;
typedef _Float16 hv32 __attribute__((ext_vector_type(32)));  // 16 VGPRs, SSA value
typedef float    fv16 __attribute__((ext_vector_type(16)));  // 16 VGPRs, SSA value

// ---------------- kernel 1: encoder -> feat[121] (unchanged, verified) ----------------
__global__ __launch_bounds__(256) void enc_kernel(
    const float* __restrict__ x, const float* __restrict__ conv_w,
    const float* __restrict__ conv_b, const float* __restrict__ comp_w1,
    const float* __restrict__ comp_b1, const float* __restrict__ comp_w2,
    const float* __restrict__ comp_b2, float* __restrict__ feat_out)
{
    const int n = blockIdx.x;     // node
    const int tid = threadIdx.x;
    float acc[8] = {0.f,0.f,0.f,0.f,0.f,0.f,0.f,0.f};
    for (int i = tid; i < BL; i += 256) {
        const float xv = x[i * NN + n];
        const float4* w4 = reinterpret_cast<const float4*>(conv_w + i * 8);
        const float4 a = w4[0], b = w4[1];
        acc[0] += xv * a.x; acc[1] += xv * a.y; acc[2] += xv * a.z; acc[3] += xv * a.w;
        acc[4] += xv * b.x; acc[5] += xv * b.y; acc[6] += xv * b.z; acc[7] += xv * b.w;
    }
    __shared__ float red[256][9];   // pad 9: conflict-free
    __shared__ float hred[32];
    #pragma unroll
    for (int j = 0; j < 8; ++j) red[tid][j] = acc[j];
    __syncthreads();
    for (int s = 128; s > 0; s >>= 1) {
        if (tid < s) {
            #pragma unroll
            for (int j = 0; j < 8; ++j) red[tid][j] += red[tid + s][j];
        }
        __syncthreads();
    }
    if (tid < 32) {
        float g[8];
        #pragma unroll
        for (int j = 0; j < 8; ++j) g[j] = red[0][j] + conv_b[j];
        float hsum = comp_b1[tid];
        #pragma unroll
        for (int j = 0; j < 8; ++j)
            hsum += g[j] * (comp_w1[j * 32 + tid] + comp_w1[(j + 8) * 32 + tid]);
        const float hv = hsum > 0.f ? hsum : 0.01f * hsum;   // leaky
        hred[tid] = hv * comp_w2[tid];
    }
    __syncthreads();
    if (tid == 0) {
        float f = comp_b2[0];
        #pragma unroll
        for (int m = 0; m < 32; ++m) f += hred[m];
        feat_out[n] = f;
    }
}

// ---------------- kernel 2: sequential mamba chain (1 block, vector-reg weights) ----------------
__device__ __forceinline__ float softplus_f(float v) {
    return v > 20.f ? v : log1pf(expf(v));
}

// classic streaming matvec (used once, for adapter)
template<int ROWS, int COLS, int ACT>
__device__ __forceinline__ void matvec4(
    const float* __restrict__ W, const float* __restrict__ bias,
    const float* in, float* out, float* red, int tid)
{
    const int slice = tid >> 7;       // 0..3
    const int j = tid & 127;
    float a0 = 0.f, a1 = 0.f, a2 = 0.f, a3 = 0.f;
    if (j < COLS) {
        const int r0 = (ROWS * slice) >> 2;
        const int r1 = (ROWS * (slice + 1)) >> 2;
        int i = r0;
        #pragma unroll 2
        for (; i + 4 <= r1; i += 4) {
            a0 += in[i + 0] * W[(i + 0) * COLS + j];
            a1 += in[i + 1] * W[(i + 1) * COLS + j];
            a2 += in[i + 2] * W[(i + 2) * COLS + j];
            a3 += in[i + 3] * W[(i + 3) * COLS + j];
        }
        for (; i < r1; ++i) a0 += in[i] * W[i * COLS + j];
    }
    red[tid] = (a0 + a1) + (a2 + a3);
    __syncthreads();
    if (tid < COLS) {
        float s = red[tid] + red[tid + 128] + red[tid + 256] + red[tid + 384] + bias[tid];
        if (ACT == 1) s = fmaxf(s, 0.f);
        else if (ACT == 2) s = tanhf(s);
        out[tid] = s;
    }
    __syncthreads();
}

// load one hv32: half e = padded row (r0+e); identity map, rows>=R or j>=COLS -> 0
template<int R, int COLS>
__device__ __forceinline__ hv32 load_w32(const float* __restrict__ W, int tid)
{
    const int slice = tid >> 7, j = tid & 127;
    const int r0 = 32 * slice;
    const bool jv = (j < COLS);
    hv32 v;
    #pragma unroll
    for (int e = 0; e < 32; ++e) {
        const int rp = r0 + e;
        v[e] = (h16)((jv && rp < R) ? W[rp * COLS + j] : 0.f);
    }
    return v;
}

// vector-reg matvec, PADR=128: 4 slices x 32 rows; in = LDS fp32, 16B aligned, pads zero
template<int COLS, int ACT>
__device__ __forceinline__ void matvec_v32(
    const hv32 w, const float* __restrict__ biasLds,
    const float* in, float* out, float* red, int tid)
{
    const int slice = tid >> 7;
    const float4* in4 = reinterpret_cast<const float4*>(in + 32 * slice);
    float acc0 = 0.f, acc1 = 0.f;
    #pragma unroll
    for (int m = 0; m < 8; ++m) {
        const float4 q = in4[m];
        acc0 += q.x * (float)w[4 * m]     + q.y * (float)w[4 * m + 1];
        acc1 += q.z * (float)w[4 * m + 2] + q.w * (float)w[4 * m + 3];
    }
    red[tid] = acc0 + acc1;
    __syncthreads();
    if (tid < COLS) {
        float s = red[tid] + red[tid + 128] + red[tid + 256] + red[tid + 384] + biasLds[tid];
        if (ACT == 1) s = fmaxf(s, 0.f);
        else if (ACT == 2) s = tanhf(s);
        out[tid] = s;
    }
    __syncthreads();
}

// vector-reg matvec, PADR=256: 4 slices x 64 rows (two hv32 per thread)
template<int COLS, int ACT>
__device__ __forceinline__ void matvec_v64(
    const hv32 wa, const hv32 wb, const float* __restrict__ biasLds,
    const float* in, float* out, float* red, int tid)
{
    const int slice = tid >> 7;
    const float4* in4 = reinterpret_cast<const float4*>(in + 64 * slice);
    float acc0 = 0.f, acc1 = 0.f;
    #pragma unroll
    for (int m = 0; m < 8; ++m) {
        const float4 q = in4[m];
        acc0 += q.x * (float)wa[4 * m]     + q.y * (float)wa[4 * m + 1];
        acc1 += q.z * (float)wa[4 * m + 2] + q.w * (float)wa[4 * m + 3];
    }
    #pragma unroll
    for (int m = 0; m < 8; ++m) {
        const float4 q = in4[m + 8];
        acc0 += q.x * (float)wb[4 * m]     + q.y * (float)wb[4 * m + 1];
        acc1 += q.z * (float)wb[4 * m + 2] + q.w * (float)wb[4 * m + 3];
    }
    red[tid] = acc0 + acc1;
    __syncthreads();
    if (tid < COLS) {
        float s = red[tid] + red[tid + 128] + red[tid + 256] + red[tid + 384] + biasLds[tid];
        if (ACT == 1) s = fmaxf(s, 0.f);
        else if (ACT == 2) s = tanhf(s);
        out[tid] = s;
    }
    __syncthreads();
}

// __launch_bounds__(512, 2): 8 waves = 2 waves/SIMD -> VGPR cap 256 for the
// ~200-VGPR vector-resident working set. Weights are ext_vector SSA values
// (NOT arrays) so they cannot be demoted to scratch (rule #20 fix).
__global__ __launch_bounds__(512, 2) void mamba_kernel(
    const float* __restrict__ adapter_w, const float* __restrict__ adapter_b,
    const float* __restrict__ ln_g, const float* __restrict__ ln_b,
    const float* __restrict__ lift_w1, const float* __restrict__ lift_b1,
    const float* __restrict__ lift_w2, const float* __restrict__ lift_b2,
    const float* __restrict__ net_w1, const float* __restrict__ net_b1,
    const float* __restrict__ net_w2, const float* __restrict__ net_b2,
    const float* __restrict__ fc1_w, const float* __restrict__ fc1_b,
    const float* __restrict__ fc2_w, const float* __restrict__ fc2_b,
    const float* __restrict__ fc3_w, const float* __restrict__ fc3_b,
    const float* __restrict__ Aw, const float* __restrict__ state_init,
    const float* __restrict__ fcout_w, const float* __restrict__ fcout_b,
    const float* __restrict__ feat_in, float* __restrict__ pred_out)
{
    __shared__ __align__(16) float catP[256];   // q [0,121)+pad0, lifted [128,249)+pad0
    __shared__ __align__(16) float t1[128], t2[128], xtsP[128];
    __shared__ __align__(16) float outvP[128];
    __shared__ float deltas[128], Bms[64], Cms[64], zb[128], ftmp[128];
    __shared__ float red[512], redb[512];
    __shared__ float lb1[128], lb2[128], nb1[128], nb2[128];
    __shared__ float f1b[128], f2b[64], f3b[64], fob[128];
    __shared__ float scal[2];

    const int tid = threadIdx.x;

    // ---- per-thread vector-resident fp16 weights (loaded once, SSA values) ----
    const hv32 wl1 = load_w32<121, 128>(lift_w1, tid);
    const hv32 wl2 = load_w32<128, 121>(lift_w2, tid);
    const hv32 wn2 = load_w32<128, 121>(net_w2, tid);
    const hv32 wo  = load_w32<121, 121>(fcout_w, tid);
    hv32 wn1a, wn1b;   // net_w1: padded rows 0..120 = q, 128..248 = lifted (orig-7)
    {
        const int slice = tid >> 7, j = tid & 127;
        const int r0 = 64 * slice;
        #pragma unroll
        for (int e = 0; e < 32; ++e) {
            const int rp = r0 + e;
            const int o = rp < 121 ? rp : (rp >= 128 && rp < 249 ? rp - 7 : -1);
            wn1a[e] = (h16)((o >= 0) ? net_w1[o * 128 + j] : 0.f);
        }
        #pragma unroll
        for (int e = 0; e < 32; ++e) {
            const int rp = r0 + 32 + e;
            const int o = rp < 121 ? rp : (rp >= 128 && rp < 249 ? rp - 7 : -1);
            wn1b[e] = (h16)((o >= 0) ? net_w1[o * 128 + j] : 0.f);
        }
    }
    hv32 wfa, wfb;     // fused fc1/fc2/fc3: 2 slices x 256 threads, 64 padded rows
    {
        const int slice = tid >> 8, j = tid & 255;
        const float* Wp = nullptr; int col = 0, C = 0;
        if (j < 121)                  { Wp = fc1_w; col = j;       C = 121; }
        else if (j >= 128 && j < 192) { Wp = fc2_w; col = j - 128; C = 64; }
        else if (j >= 192)            { Wp = fc3_w; col = j - 192; C = 64; }
        const int r0 = 64 * slice;
        #pragma unroll
        for (int e = 0; e < 32; ++e) {
            const int rp = r0 + e;
            wfa[e] = (h16)((Wp && rp < 121) ? Wp[rp * C + col] : 0.f);
        }
        #pragma unroll
        for (int e = 0; e < 32; ++e) {
            const int rp = r0 + 32 + e;
            wfb[e] = (h16)((Wp && rp < 121) ? Wp[rp * C + col] : 0.f);
        }
    }

    // ---- per-thread vector h / A (chunked (c,d) as before) ----
    const int hc = tid >> 7, hd = tid & 127;
    fv16 Areg, hreg;
    #pragma unroll
    for (int k = 0; k < 16; ++k) { Areg[k] = 0.f; hreg[k] = 0.f; }
    if (hd < NN) {
        #pragma unroll
        for (int k = 0; k < 16; ++k) {
            Areg[k] = Aw[hd * SSZ + hc * 16 + k];
            hreg[k] = state_init[hd * SSZ + hc * 16 + k];
        }
    }

    // ---- biases to LDS, zero pads, feat ----
    if (tid < 128) { lb1[tid] = lift_b1[tid]; nb1[tid] = net_b1[tid]; }
    if (tid < 121) {
        lb2[tid] = lift_b2[tid]; nb2[tid] = net_b2[tid];
        f1b[tid] = fc1_b[tid];   fob[tid] = fcout_b[tid];
        ftmp[tid] = feat_in[tid];
    }
    if (tid < 64) { f2b[tid] = fc2_b[tid]; f3b[tid] = fc3_b[tid]; }
    if (tid >= 121 && tid < 128) { catP[tid] = 0.f; xtsP[tid] = 0.f; outvP[tid] = 0.f; }
    if (tid >= 249 && tid < 256) catP[tid] = 0.f;
    __syncthreads();

    // z = feat @ adapter_w + adapter_b (streamed, once)
    matvec4<NN, NN, 0>(adapter_w, adapter_b, ftmp, zb, red, tid);

    // layernorm -> q (catP[0..121))
    {
        const float v = (tid < NN) ? zb[tid] : 0.f;
        red[tid] = v; redb[tid] = v * v;
        __syncthreads();
        for (int s = 256; s > 0; s >>= 1) {
            if (tid < s) { red[tid] += red[tid + s]; redb[tid] += redb[tid + s]; }
            __syncthreads();
        }
        if (tid == 0) {
            const float mu = red[0] / (float)NN;
            const float var = redb[0] / (float)NN - mu * mu;
            scal[0] = mu; scal[1] = 1.0f / sqrtf(var + 1e-5f);
        }
        __syncthreads();
        if (tid < NN) catP[tid] = (zb[tid] - scal[0]) * scal[1] * ln_g[tid] + ln_b[tid];
        __syncthreads();
    }

    // ev 0 = warmup (h only), ev 1..6 = steps (produce pred, feed back)
    for (int ev = 0; ev < 7; ++ev) {
        matvec_v32<128, 1>(wl1, lb1, catP, t1, red, tid);               // relu
        matvec_v32<121, 2>(wl2, lb2, t1, catP + 128, red, tid);         // tanh -> lifted
        matvec_v64<128, 1>(wn1a, wn1b, nb1, catP, t2, red, tid);        // relu
        matvec_v32<121, 0>(wn2, nb2, t2, xtsP, red, tid);               // xt

        // fused delta / Bm / Cm (2 slices of 256 threads, vector weights)
        {
            const int slice = tid >> 8;
            const float4* in4 = reinterpret_cast<const float4*>(xtsP + 64 * slice);
            float acc0 = 0.f, acc1 = 0.f;
            #pragma unroll
            for (int m = 0; m < 8; ++m) {
                const float4 q = in4[m];
                acc0 += q.x * (float)wfa[4 * m]     + q.y * (float)wfa[4 * m + 1];
                acc1 += q.z * (float)wfa[4 * m + 2] + q.w * (float)wfa[4 * m + 3];
            }
            #pragma unroll
            for (int m = 0; m < 8; ++m) {
                const float4 q = in4[m + 8];
                acc0 += q.x * (float)wfb[4 * m]     + q.y * (float)wfb[4 * m + 1];
                acc1 += q.z * (float)wfb[4 * m + 2] + q.w * (float)wfb[4 * m + 3];
            }
            red[tid] = acc0 + acc1;
            __syncthreads();
            if (tid < 121)
                deltas[tid] = softplus_f(red[tid] + red[tid + 256] + f1b[tid]);
            else if (tid >= 128 && tid < 192)
                Bms[tid - 128] = red[tid] + red[tid + 256] + f2b[tid - 128];
            else if (tid >= 192 && tid < 256)
                Cms[tid - 192] = red[tid] + red[tid + 256] + f3b[tid - 192];
            __syncthreads();
        }

        // h update (vector regs) + out[d] = sum_n Cm[n]*h_new[d,n]
        {
            float acc = 0.f;
            if (hd < NN) {
                const float dd = deltas[hd];
                const float coef = xtsP[hd] * dd;
                #pragma unroll
                for (int k = 0; k < 16; ++k) {
                    const float s = dd * Areg[k];
                    const float cel = s > 0.f ? s : expm1f(s);   // celu, alpha=1
                    const float dAv = expf(-cel);
                    const float hn = dAv * hreg[k] + coef * Bms[hc * 16 + k];
                    hreg[k] = hn;
                    acc += Cms[hc * 16 + k] * hn;
                }
            }
            red[tid] = acc;
            __syncthreads();
            if (tid < NN) outvP[tid] = red[tid] + red[tid + 128] + red[tid + 256] + red[tid + 384];
            __syncthreads();
        }

        if (ev > 0) {
            matvec_v32<121, 0>(wo, fob, outvP, catP, red, tid);         // pred -> q
            if (tid < NN) pred_out[(ev - 1) * NN + tid] = catP[tid];
            __syncthreads();
        }
    }
}

// ---------------- kernel 3: broadcast preds to (steps,b,l,m) ----------------
__global__ __launch_bounds__(128) void bcast_kernel(
    const float* __restrict__ pred, float* __restrict__ out)
{
    const int row = blockIdx.x;            // s*3072 + (b*24+l), 18432 rows
    const int s = row / BL;
    const int t = threadIdx.x;
    if (t < NN) out[row * NN + t] = pred[s * NN + t];
}

extern "C" void kernel_launch(void* const* d_in, const int* in_sizes, int n_in,
                              void* d_out, int out_size, void* d_ws, size_t ws_size,
                              hipStream_t stream)
{
    const float* x        = (const float*)d_in[0];
    const float* conv_w   = (const float*)d_in[3];
    const float* conv_b   = (const float*)d_in[4];
    const float* comp_w1  = (const float*)d_in[5];
    const float* comp_b1  = (const float*)d_in[6];
    const float* comp_w2  = (const float*)d_in[7];
    const float* comp_b2  = (const float*)d_in[8];
    const float* adapter_w= (const float*)d_in[9];
    const float* adapter_b= (const float*)d_in[10];
    const float* ln_g     = (const float*)d_in[11];
    const float* ln_b     = (const float*)d_in[12];
    const float* lift_w1  = (const float*)d_in[13];
    const float* lift_b1  = (const float*)d_in[14];
    const float* lift_w2  = (const float*)d_in[15];
    const float* lift_b2  = (const float*)d_in[16];
    const float* net_w1   = (const float*)d_in[17];
    const float* net_b1   = (const float*)d_in[18];
    const float* net_w2   = (const float*)d_in[19];
    const float* net_b2   = (const float*)d_in[20];
    const float* fc1_w    = (const float*)d_in[21];
    const float* fc1_b    = (const float*)d_in[22];
    const float* fc2_w    = (const float*)d_in[23];
    const float* fc2_b    = (const float*)d_in[24];
    const float* fc3_w    = (const float*)d_in[25];
    const float* fc3_b    = (const float*)d_in[26];
    const float* Aw       = (const float*)d_in[27];
    const float* state_in = (const float*)d_in[28];
    const float* fcout_w  = (const float*)d_in[29];
    const float* fcout_b  = (const float*)d_in[30];

    float* ws   = (float*)d_ws;
    float* feat = ws;          // 121 floats
    float* pred = ws + 128;    // 6*121 floats

    enc_kernel<<<NN, 256, 0, stream>>>(x, conv_w, conv_b, comp_w1, comp_b1,
                                       comp_w2, comp_b2, feat);
    mamba_kernel<<<1, 512, 0, stream>>>(adapter_w, adapter_b, ln_g, ln_b,
        lift_w1, lift_b1, lift_w2, lift_b2, net_w1, net_b1, net_w2, net_b2,
        fc1_w, fc1_b, fc2_w, fc2_b, fc3_w, fc3_b, Aw, state_in,
        fcout_w, fcout_b, feat, pred);
    bcast_kernel<<<NSTEPS * BL, 128, 0, stream>>>(pred, (float*)d_out);
}

// Round 13
// 282.774 us; speedup vs baseline: 1.1559x; 1.1442x over previous
//
#include <hip/hip_runtime.h>
#include <hip/hip_bf16.h>
#include <math.h>

#define BATCH 128
#define LSEQ 24
#define NN 121      // nodes == d_model == out feature
#define SSZ 64      // state size
#define NSTEPS 6
#define BL 3072     // BATCH*LSEQ
#define NT 1024     // mamba block size (16 waves -> natural 128-VGPR budget)

typedef _Float16 h16;
typedef _Float16 hv16 __attribute__((ext_vector_type(16)));  // 8 VGPRs
typedef _Float16 hv32 __attribute__((ext_vector_type(32)));  // 16 VGPRs
typedef float    fv8  __attribute__((ext_vector_type(8)));   // 8 VGPRs

// ---------------- kernel 1: encoder -> feat[121] (unchanged, verified) ----------------
__global__ __launch_bounds__(256) void enc_kernel(
    const float* __restrict__ x, const float* __restrict__ conv_w,
    const float* __restrict__ conv_b, const float* __restrict__ comp_w1,
    const float* __restrict__ comp_b1, const float* __restrict__ comp_w2,
    const float* __restrict__ comp_b2, float* __restrict__ feat_out)
{
    const int n = blockIdx.x;     // node
    const int tid = threadIdx.x;
    float acc[8] = {0.f,0.f,0.f,0.f,0.f,0.f,0.f,0.f};
    for (int i = tid; i < BL; i += 256) {
        const float xv = x[i * NN + n];
        const float4* w4 = reinterpret_cast<const float4*>(conv_w + i * 8);
        const float4 a = w4[0], b = w4[1];
        acc[0] += xv * a.x; acc[1] += xv * a.y; acc[2] += xv * a.z; acc[3] += xv * a.w;
        acc[4] += xv * b.x; acc[5] += xv * b.y; acc[6] += xv * b.z; acc[7] += xv * b.w;
    }
    __shared__ float red[256][9];   // pad 9: conflict-free
    __shared__ float hred[32];
    #pragma unroll
    for (int j = 0; j < 8; ++j) red[tid][j] = acc[j];
    __syncthreads();
    for (int s = 128; s > 0; s >>= 1) {
        if (tid < s) {
            #pragma unroll
            for (int j = 0; j < 8; ++j) red[tid][j] += red[tid + s][j];
        }
        __syncthreads();
    }
    if (tid < 32) {
        float g[8];
        #pragma unroll
        for (int j = 0; j < 8; ++j) g[j] = red[0][j] + conv_b[j];
        float hsum = comp_b1[tid];
        #pragma unroll
        for (int j = 0; j < 8; ++j)
            hsum += g[j] * (comp_w1[j * 32 + tid] + comp_w1[(j + 8) * 32 + tid]);
        const float hv = hsum > 0.f ? hsum : 0.01f * hsum;   // leaky
        hred[tid] = hv * comp_w2[tid];
    }
    __syncthreads();
    if (tid == 0) {
        float f = comp_b2[0];
        #pragma unroll
        for (int m = 0; m < 32; ++m) f += hred[m];
        feat_out[n] = f;
    }
}

// ---------------- kernel 2: sequential mamba chain (1 block x 1024 thr) ----------------
__device__ __forceinline__ float softplus_f(float v) {
    return v > 20.f ? v : log1pf(expf(v));
}

// streaming matvec, 8 row-slices (used once, for adapter)
template<int ROWS, int COLS, int ACT>
__device__ __forceinline__ void matvec8(
    const float* __restrict__ W, const float* __restrict__ bias,
    const float* in, float* out, float* red, int tid)
{
    const int slice = tid >> 7;       // 0..7
    const int j = tid & 127;
    float a0 = 0.f;
    if (j < COLS) {
        const int r0 = (ROWS * slice) >> 3;
        const int r1 = (ROWS * (slice + 1)) >> 3;
        for (int i = r0; i < r1; ++i) a0 += in[i] * W[i * COLS + j];
    }
    red[tid] = a0;
    __syncthreads();
    if (tid < COLS) {
        float s = bias[tid];
        #pragma unroll
        for (int c = 0; c < 8; ++c) s += red[tid + 128 * c];
        if (ACT == 1) s = fmaxf(s, 0.f);
        else if (ACT == 2) s = tanhf(s);
        out[tid] = s;
    }
    __syncthreads();
}

// load hv16: 8 slices x 16 padded rows, identity map; rows>=R or j>=COLS -> 0
template<int R, int COLS>
__device__ __forceinline__ hv16 load_w16(const float* __restrict__ W, int tid)
{
    const int slice = tid >> 7, j = tid & 127;
    const int r0 = 16 * slice;
    const bool jv = (j < COLS);
    hv16 v;
    #pragma unroll
    for (int e = 0; e < 16; ++e) {
        const int rp = r0 + e;
        v[e] = (h16)((jv && rp < R) ? W[rp * COLS + j] : 0.f);
    }
    return v;
}

// vector-reg matvec, PADR=128: 8 slices x 16 rows; in = LDS fp32, 16B aligned, pads zero
template<int COLS, int ACT>
__device__ __forceinline__ void matvec_v16(
    const hv16 w, const float* __restrict__ biasLds,
    const float* in, float* out, float* red, int tid)
{
    const int slice = tid >> 7;
    const float4* in4 = reinterpret_cast<const float4*>(in + 16 * slice);
    float acc0 = 0.f, acc1 = 0.f;
    #pragma unroll
    for (int m = 0; m < 4; ++m) {
        const float4 q = in4[m];
        acc0 += q.x * (float)w[4 * m]     + q.y * (float)w[4 * m + 1];
        acc1 += q.z * (float)w[4 * m + 2] + q.w * (float)w[4 * m + 3];
    }
    red[tid] = acc0 + acc1;
    __syncthreads();
    if (tid < COLS) {
        float s = biasLds[tid];
        #pragma unroll
        for (int c = 0; c < 8; ++c) s += red[tid + 128 * c];
        if (ACT == 1) s = fmaxf(s, 0.f);
        else if (ACT == 2) s = tanhf(s);
        out[tid] = s;
    }
    __syncthreads();
}

// vector-reg matvec, PADR=256 (wn1): 8 slices x 32 rows
template<int COLS, int ACT>
__device__ __forceinline__ void matvec_v32w(
    const hv32 w, const float* __restrict__ biasLds,
    const float* in, float* out, float* red, int tid)
{
    const int slice = tid >> 7;
    const float4* in4 = reinterpret_cast<const float4*>(in + 32 * slice);
    float acc0 = 0.f, acc1 = 0.f;
    #pragma unroll
    for (int m = 0; m < 8; ++m) {
        const float4 q = in4[m];
        acc0 += q.x * (float)w[4 * m]     + q.y * (float)w[4 * m + 1];
        acc1 += q.z * (float)w[4 * m + 2] + q.w * (float)w[4 * m + 3];
    }
    red[tid] = acc0 + acc1;
    __syncthreads();
    if (tid < COLS) {
        float s = biasLds[tid];
        #pragma unroll
        for (int c = 0; c < 8; ++c) s += red[tid + 128 * c];
        if (ACT == 1) s = fmaxf(s, 0.f);
        else if (ACT == 2) s = tanhf(s);
        out[tid] = s;
    }
    __syncthreads();
}

__global__ __launch_bounds__(NT) void mamba_kernel(
    const float* __restrict__ adapter_w, const float* __restrict__ adapter_b,
    const float* __restrict__ ln_g, const float* __restrict__ ln_b,
    const float* __restrict__ lift_w1, const float* __restrict__ lift_b1,
    const float* __restrict__ lift_w2, const float* __restrict__ lift_b2,
    const float* __restrict__ net_w1, const float* __restrict__ net_b1,
    const float* __restrict__ net_w2, const float* __restrict__ net_b2,
    const float* __restrict__ fc1_w, const float* __restrict__ fc1_b,
    const float* __restrict__ fc2_w, const float* __restrict__ fc2_b,
    const float* __restrict__ fc3_w, const float* __restrict__ fc3_b,
    const float* __restrict__ Aw, const float* __restrict__ state_init,
    const float* __restrict__ fcout_w, const float* __restrict__ fcout_b,
    const float* __restrict__ feat_in, float* __restrict__ pred_out)
{
    __shared__ __align__(16) float catP[256];   // q [0,121)+pad0, lifted [128,249)+pad0
    __shared__ __align__(16) float t1[128], t2[128], xtsP[128];
    __shared__ __align__(16) float outvP[128];
    __shared__ float deltas[128], Bms[64], Cms[64], zb[128], ftmp[128];
    __shared__ float red[NT], redb[NT];
    __shared__ float lb1[128], lb2[128], nb1[128], nb2[128];
    __shared__ float f1b[128], f2b[64], f3b[64], fob[128];
    __shared__ float scal[2];

    const int tid = threadIdx.x;

    // ---- per-thread vector-resident fp16 weights (SSA values, ~64 VGPRs) ----
    const hv16 wl1 = load_w16<121, 128>(lift_w1, tid);
    const hv16 wl2 = load_w16<128, 121>(lift_w2, tid);
    const hv16 wn2 = load_w16<128, 121>(net_w2, tid);
    const hv16 wo  = load_w16<121, 121>(fcout_w, tid);
    hv32 wn1;          // net_w1: padded rows 0..120 = q, 128..248 = lifted (orig-7)
    {
        const int slice = tid >> 7, j = tid & 127;
        const int r0 = 32 * slice;
        #pragma unroll
        for (int e = 0; e < 32; ++e) {
            const int rp = r0 + e;
            const int o = rp < 121 ? rp : (rp >= 128 && rp < 249 ? rp - 7 : -1);
            wn1[e] = (h16)((o >= 0) ? net_w1[o * 128 + j] : 0.f);
        }
    }
    hv32 wf;           // fused fc1/fc2/fc3: 4 slices x 256 cols, 32 padded rows each
    {
        const int slice = tid >> 8, j = tid & 255;
        const float* Wp = nullptr; int col = 0, C = 0;
        if (j < 121)                  { Wp = fc1_w; col = j;       C = 121; }
        else if (j >= 128 && j < 192) { Wp = fc2_w; col = j - 128; C = 64; }
        else if (j >= 192)            { Wp = fc3_w; col = j - 192; C = 64; }
        const int r0 = 32 * slice;
        #pragma unroll
        for (int e = 0; e < 32; ++e) {
            const int rp = r0 + e;
            wf[e] = (h16)((Wp && rp < 121) ? Wp[rp * C + col] : 0.f);
        }
    }

    // ---- per-thread vector h / A: 8 chunks x 8 n-values ----
    const int hc = tid >> 7, hd = tid & 127;   // hc in [0,8)
    fv8 Areg, hreg;
    #pragma unroll
    for (int k = 0; k < 8; ++k) { Areg[k] = 0.f; hreg[k] = 0.f; }
    if (hd < NN) {
        #pragma unroll
        for (int k = 0; k < 8; ++k) {
            Areg[k] = Aw[hd * SSZ + hc * 8 + k];
            hreg[k] = state_init[hd * SSZ + hc * 8 + k];
        }
    }

    // ---- biases to LDS, zero pads, feat ----
    if (tid < 128) { lb1[tid] = lift_b1[tid]; nb1[tid] = net_b1[tid]; }
    if (tid < 121) {
        lb2[tid] = lift_b2[tid]; nb2[tid] = net_b2[tid];
        f1b[tid] = fc1_b[tid];   fob[tid] = fcout_b[tid];
        ftmp[tid] = feat_in[tid];
    }
    if (tid < 64) { f2b[tid] = fc2_b[tid]; f3b[tid] = fc3_b[tid]; }
    if (tid >= 121 && tid < 128) { catP[tid] = 0.f; xtsP[tid] = 0.f; outvP[tid] = 0.f; }
    if (tid >= 249 && tid < 256) catP[tid] = 0.f;
    __syncthreads();

    // z = feat @ adapter_w + adapter_b (streamed, once)
    matvec8<NN, NN, 0>(adapter_w, adapter_b, ftmp, zb, red, tid);

    // layernorm -> q (catP[0..121))
    {
        const float v = (tid < NN) ? zb[tid] : 0.f;
        red[tid] = v; redb[tid] = v * v;
        __syncthreads();
        for (int s = NT / 2; s > 0; s >>= 1) {
            if (tid < s) { red[tid] += red[tid + s]; redb[tid] += redb[tid + s]; }
            __syncthreads();
        }
        if (tid == 0) {
            const float mu = red[0] / (float)NN;
            const float var = redb[0] / (float)NN - mu * mu;
            scal[0] = mu; scal[1] = 1.0f / sqrtf(var + 1e-5f);
        }
        __syncthreads();
        if (tid < NN) catP[tid] = (zb[tid] - scal[0]) * scal[1] * ln_g[tid] + ln_b[tid];
        __syncthreads();
    }

    // ev 0 = warmup (h only), ev 1..6 = steps (produce pred, feed back)
    for (int ev = 0; ev < 7; ++ev) {
        matvec_v16<128, 1>(wl1, lb1, catP, t1, red, tid);           // relu
        matvec_v16<121, 2>(wl2, lb2, t1, catP + 128, red, tid);     // tanh -> lifted
        matvec_v32w<128, 1>(wn1, nb1, catP, t2, red, tid);          // relu (PADR=256)
        matvec_v16<121, 0>(wn2, nb2, t2, xtsP, red, tid);           // xt

        // fused delta / Bm / Cm (4 slices x 256 cols, vector weights)
        {
            const int slice = tid >> 8;
            const float4* in4 = reinterpret_cast<const float4*>(xtsP + 32 * slice);
            float acc0 = 0.f, acc1 = 0.f;
            #pragma unroll
            for (int m = 0; m < 8; ++m) {
                const float4 q = in4[m];
                acc0 += q.x * (float)wf[4 * m]     + q.y * (float)wf[4 * m + 1];
                acc1 += q.z * (float)wf[4 * m + 2] + q.w * (float)wf[4 * m + 3];
            }
            red[tid] = acc0 + acc1;
            __syncthreads();
            if (tid < 256) {
                const float val = red[tid] + red[tid + 256] + red[tid + 512] + red[tid + 768];
                if (tid < 121)
                    deltas[tid] = softplus_f(val + f1b[tid]);
                else if (tid >= 128 && tid < 192)
                    Bms[tid - 128] = val + f2b[tid - 128];
                else if (tid >= 192)
                    Cms[tid - 192] = val + f3b[tid - 192];
            }
            __syncthreads();
        }

        // h update (vector regs, 8 n per thread) + out[d] = sum_n Cm[n]*h_new[d,n]
        {
            float acc = 0.f;
            if (hd < NN) {
                const float dd = deltas[hd];
                const float coef = xtsP[hd] * dd;
                #pragma unroll
                for (int k = 0; k < 8; ++k) {
                    const float s = dd * Areg[k];
                    const float cel = s > 0.f ? s : expm1f(s);   // celu, alpha=1
                    const float dAv = expf(-cel);
                    const float hn = dAv * hreg[k] + coef * Bms[hc * 8 + k];
                    hreg[k] = hn;
                    acc += Cms[hc * 8 + k] * hn;
                }
            }
            red[tid] = acc;
            __syncthreads();
            if (tid < NN) {
                float s = 0.f;
                #pragma unroll
                for (int c = 0; c < 8; ++c) s += red[tid + 128 * c];
                outvP[tid] = s;
            }
            __syncthreads();
        }

        if (ev > 0) {
            matvec_v16<121, 0>(wo, fob, outvP, catP, red, tid);     // pred -> q
            if (tid < NN) pred_out[(ev - 1) * NN + tid] = catP[tid];
            __syncthreads();
        }
    }
}

// ---------------- kernel 3: broadcast preds to (steps,b,l,m) ----------------
__global__ __launch_bounds__(128) void bcast_kernel(
    const float* __restrict__ pred, float* __restrict__ out)
{
    const int row = blockIdx.x;            // s*3072 + (b*24+l), 18432 rows
    const int s = row / BL;
    const int t = threadIdx.x;
    if (t < NN) out[row * NN + t] = pred[s * NN + t];
}

extern "C" void kernel_launch(void* const* d_in, const int* in_sizes, int n_in,
                              void* d_out, int out_size, void* d_ws, size_t ws_size,
                              hipStream_t stream)
{
    const float* x        = (const float*)d_in[0];
    const float* conv_w   = (const float*)d_in[3];
    const float* conv_b   = (const float*)d_in[4];
    const float* comp_w1  = (const float*)d_in[5];
    const float* comp_b1  = (const float*)d_in[6];
    const float* comp_w2  = (const float*)d_in[7];
    const float* comp_b2  = (const float*)d_in[8];
    const float* adapter_w= (const float*)d_in[9];
    const float* adapter_b= (const float*)d_in[10];
    const float* ln_g     = (const float*)d_in[11];
    const float* ln_b     = (const float*)d_in[12];
    const float* lift_w1  = (const float*)d_in[13];
    const float* lift_b1  = (const float*)d_in[14];
    const float* lift_w2  = (const float*)d_in[15];
    const float* lift_b2  = (const float*)d_in[16];
    const float* net_w1   = (const float*)d_in[17];
    const float* net_b1   = (const float*)d_in[18];
    const float* net_w2   = (const float*)d_in[19];
    const float* net_b2   = (const float*)d_in[20];
    const float* fc1_w    = (const float*)d_in[21];
    const float* fc1_b    = (const float*)d_in[22];
    const float* fc2_w    = (const float*)d_in[23];
    const float* fc2_b    = (const float*)d_in[24];
    const float* fc3_w    = (const float*)d_in[25];
    const float* fc3_b    = (const float*)d_in[26];
    const float* Aw       = (const float*)d_in[27];
    const float* state_in = (const float*)d_in[28];
    const float* fcout_w  = (const float*)d_in[29];
    const float* fcout_b  = (const float*)d_in[30];

    float* ws   = (float*)d_ws;
    float* feat = ws;          // 121 floats
    float* pred = ws + 128;    // 6*121 floats

    enc_kernel<<<NN, 256, 0, stream>>>(x, conv_w, conv_b, comp_w1, comp_b1,
                                       comp_w2, comp_b2, feat);
    mamba_kernel<<<1, NT, 0, stream>>>(adapter_w, adapter_b, ln_g, ln_b,
        lift_w1, lift_b1, lift_w2, lift_b2, net_w1, net_b1, net_w2, net_b2,
        fc1_w, fc1_b, fc2_w, fc2_b, fc3_w, fc3_b, Aw, state_in,
        fcout_w, fcout_b, feat, pred);
    bcast_kernel<<<NSTEPS * BL, 128, 0, stream>>>(pred, (float*)d_out);
}

// Round 14
// 179.680 us; speedup vs baseline: 1.8191x; 1.5738x over previous
//
#include <hip/hip_runtime.h>
#include <hip/hip_bf16.h>
#include <math.h>

#define BATCH 128
#define LSEQ 24
#define NN 121      // nodes == d_model == out feature
#define SSZ 64      // state size
#define NSTEPS 6
#define BL 3072     // BATCH*LSEQ
#define NT 1024     // mamba block size

typedef _Float16 h16;
typedef _Float16 h16x2 __attribute__((ext_vector_type(2)));
typedef float    fv8  __attribute__((ext_vector_type(8)));

// ws packed fp16 weight region (u16 element offsets), base at byte 4096
#define OFF_WL1 0        // [64 pairs][128 cols]  lift_w1 (R=121,C=128)
#define OFF_WL2 16384    // [64][128]             lift_w2 (R=128,C=121)
#define OFF_WN2 32768    // [64][128]             net_w2  (R=128,C=121)
#define OFF_WO  49152    // [64][128]             fcout_w (R=121,C=121)
#define OFF_WN1 65536    // [128][128]            net_w1 remapped to 256 padded rows
#define OFF_WF  98304    // [64][256]             fused fc1/fc2/fc3 (121 rows)
#define TOT_HALVES 131072

__device__ __forceinline__ h16x2 u2h(uint32_t u) {
    union { uint32_t u; h16x2 h; } c; c.u = u; return c.h;
}
__device__ __forceinline__ uint16_t f2u16(float v) {
    union { h16 h; uint16_t u; } c; c.h = (h16)v; return c.u;
}

// ---------------- kernel 1: encoder -> feat[121] (unchanged, verified) ----------------
__global__ __launch_bounds__(256) void enc_kernel(
    const float* __restrict__ x, const float* __restrict__ conv_w,
    const float* __restrict__ conv_b, const float* __restrict__ comp_w1,
    const float* __restrict__ comp_b1, const float* __restrict__ comp_w2,
    const float* __restrict__ comp_b2, float* __restrict__ feat_out)
{
    const int n = blockIdx.x;
    const int tid = threadIdx.x;
    float acc[8] = {0.f,0.f,0.f,0.f,0.f,0.f,0.f,0.f};
    for (int i = tid; i < BL; i += 256) {
        const float xv = x[i * NN + n];
        const float4* w4 = reinterpret_cast<const float4*>(conv_w + i * 8);
        const float4 a = w4[0], b = w4[1];
        acc[0] += xv * a.x; acc[1] += xv * a.y; acc[2] += xv * a.z; acc[3] += xv * a.w;
        acc[4] += xv * b.x; acc[5] += xv * b.y; acc[6] += xv * b.z; acc[7] += xv * b.w;
    }
    __shared__ float red[256][9];
    __shared__ float hred[32];
    #pragma unroll
    for (int j = 0; j < 8; ++j) red[tid][j] = acc[j];
    __syncthreads();
    for (int s = 128; s > 0; s >>= 1) {
        if (tid < s) {
            #pragma unroll
            for (int j = 0; j < 8; ++j) red[tid][j] += red[tid + s][j];
        }
        __syncthreads();
    }
    if (tid < 32) {
        float g[8];
        #pragma unroll
        for (int j = 0; j < 8; ++j) g[j] = red[0][j] + conv_b[j];
        float hsum = comp_b1[tid];
        #pragma unroll
        for (int j = 0; j < 8; ++j)
            hsum += g[j] * (comp_w1[j * 32 + tid] + comp_w1[(j + 8) * 32 + tid]);
        const float hv = hsum > 0.f ? hsum : 0.01f * hsum;
        hred[tid] = hv * comp_w2[tid];
    }
    __syncthreads();
    if (tid == 0) {
        float f = comp_b2[0];
        #pragma unroll
        for (int m = 0; m < 32; ++m) f += hred[m];
        feat_out[n] = f;
    }
}

// ---------------- kernel 1b: pack all weights to fp16 row-pair layout in ws ----------
__global__ __launch_bounds__(256) void prep_kernel(
    const float* __restrict__ lift_w1, const float* __restrict__ lift_w2,
    const float* __restrict__ net_w1,  const float* __restrict__ net_w2,
    const float* __restrict__ fc1_w,   const float* __restrict__ fc2_w,
    const float* __restrict__ fc3_w,   const float* __restrict__ fcout_w,
    uint16_t* __restrict__ ws16)
{
    const int i = blockIdx.x * 256 + threadIdx.x;
    if (i >= TOT_HALVES) return;
    float v = 0.f;
    if (i < OFF_WL2) {                    // wl1: R=121, C=128, COLSP=128
        const int l = i, e = l & 1, j = (l >> 1) & 127, pp = l >> 8;
        const int rp = 2 * pp + e;
        if (rp < 121) v = lift_w1[rp * 128 + j];
    } else if (i < OFF_WN2) {             // wl2: R=128, C=121
        const int l = i - OFF_WL2, e = l & 1, j = (l >> 1) & 127, pp = l >> 8;
        const int rp = 2 * pp + e;
        if (j < 121 && rp < 128) v = lift_w2[rp * 121 + j];
    } else if (i < OFF_WO) {              // wn2: R=128, C=121
        const int l = i - OFF_WN2, e = l & 1, j = (l >> 1) & 127, pp = l >> 8;
        const int rp = 2 * pp + e;
        if (j < 121 && rp < 128) v = net_w2[rp * 121 + j];
    } else if (i < OFF_WN1) {             // wo: R=121, C=121
        const int l = i - OFF_WO, e = l & 1, j = (l >> 1) & 127, pp = l >> 8;
        const int rp = 2 * pp + e;
        if (j < 121 && rp < 121) v = fcout_w[rp * 121 + j];
    } else if (i < OFF_WF) {              // wn1: padded rows 0..255; 0..120=q, 128..248=lifted(-7)
        const int l = i - OFF_WN1, e = l & 1, j = (l >> 1) & 127, pp = l >> 8;
        const int rp = 2 * pp + e;
        const int o = rp < 121 ? rp : (rp >= 128 && rp < 249 ? rp - 7 : -1);
        if (o >= 0) v = net_w1[o * 128 + j];
    } else {                              // wf: fused fc1/fc2/fc3, rows 121 pad 128, COLSP=256
        const int l = i - OFF_WF, e = l & 1, j = (l >> 1) & 255, pp = l >> 9;
        const int rp = 2 * pp + e;
        if (rp < 121) {
            if (j < 121)                 v = fc1_w[rp * 121 + j];
            else if (j >= 128 && j < 192) v = fc2_w[rp * 64 + (j - 128)];
            else if (j >= 192)            v = fc3_w[rp * 64 + (j - 192)];
        }
    }
    ws16[i] = f2u16(v);
}

// ---------------- kernel 2: sequential mamba chain ----------------
__device__ __forceinline__ float softplus_f(float v) {
    return v > 20.f ? v : log1pf(expf(v));
}

// streaming fp32 matvec, 8 row-slices (used once, for adapter)
template<int ROWS, int COLS, int ACT>
__device__ __forceinline__ void matvec8(
    const float* __restrict__ W, const float* __restrict__ bias,
    const float* in, float* out, float* red, int tid)
{
    const int slice = tid >> 7;
    const int j = tid & 127;
    float a0 = 0.f;
    if (j < COLS) {
        const int r0 = (ROWS * slice) >> 3;
        const int r1 = (ROWS * (slice + 1)) >> 3;
        for (int i = r0; i < r1; ++i) a0 += in[i] * W[i * COLS + j];
    }
    red[tid] = a0;
    __syncthreads();
    if (tid < COLS) {
        float s = bias[tid];
        #pragma unroll
        for (int c = 0; c < 8; ++c) s += red[tid + 128 * c];
        if (ACT == 1) s = fmaxf(s, 0.f);
        else if (ACT == 2) s = tanhf(s);
        out[tid] = s;
    }
    __syncthreads();
}

// streamed fp16-pair matvec from ws: [64 pairs][128 cols], PADR=128
template<int COLS, int ACT>
__device__ __forceinline__ void stream_mv(
    const uint32_t* __restrict__ g, const float* __restrict__ biasLds,
    const float* in, float* out, float* red, int tid)
{
    const int s = tid >> 7, j = tid & 127;
    float acc = 0.f;
    #pragma unroll
    for (int p = 0; p < 8; ++p) {
        const h16x2 h = u2h(g[(s * 8 + p) * 128 + j]);
        const int r = s * 16 + 2 * p;
        acc += in[r] * (float)h.x + in[r + 1] * (float)h.y;
    }
    red[tid] = acc;
    __syncthreads();
    if (tid < COLS) {
        float v = biasLds[tid];
        #pragma unroll
        for (int c = 0; c < 8; ++c) v += red[tid + 128 * c];
        if (ACT == 1) v = fmaxf(v, 0.f);
        else if (ACT == 2) v = tanhf(v);
        out[tid] = v;
    }
    __syncthreads();
}

__global__ __launch_bounds__(NT) void mamba_kernel(
    const float* __restrict__ adapter_w, const float* __restrict__ adapter_b,
    const float* __restrict__ ln_g, const float* __restrict__ ln_b,
    const float* __restrict__ lift_b1, const float* __restrict__ lift_b2,
    const float* __restrict__ net_b1,  const float* __restrict__ net_b2,
    const float* __restrict__ fc1_b,   const float* __restrict__ fc2_b,
    const float* __restrict__ fc3_b,   const float* __restrict__ fcout_b,
    const float* __restrict__ Aw, const float* __restrict__ state_init,
    const uint32_t* __restrict__ wsp,   // packed fp16 pairs (u32)
    const float* __restrict__ feat_in, float* __restrict__ pred_out)
{
    __shared__ uint32_t WN1[16384];   // 64 KB: net_w1 [128 pairs][128]
    __shared__ uint32_t WF[16384];    // 64 KB: fused fc [64 pairs][256]
    __shared__ __align__(16) float catP[256];
    __shared__ __align__(16) float t1[128], t2[128], xtsP[128], outvP[128];
    __shared__ float deltas[128], Bms[64], Cms[64];
    __shared__ float red[NT];
    __shared__ float r128[128], q128[128];
    __shared__ float lb1[128], lb2[128], nb1[128], nb2[128];
    __shared__ float f1b[128], f2b[64], f3b[64], fob[128];
    __shared__ float scal[2];

    const int tid = threadIdx.x;
    const uint32_t* WL1g = wsp;                       // u32 offsets = u16/2
    const uint32_t* WL2g = wsp + 8192;
    const uint32_t* WN2g = wsp + 16384;
    const uint32_t* WOg  = wsp + 24576;

    // LDS weight staging
    #pragma unroll
    for (int k = 0; k < 16; ++k) {
        WN1[k * NT + tid] = wsp[32768 + k * NT + tid];
        WF [k * NT + tid] = wsp[49152 + k * NT + tid];
    }

    // per-thread A / h (8 n-values each)
    const int hc = tid >> 7, hd = tid & 127;
    fv8 Areg, hreg;
    #pragma unroll
    for (int k = 0; k < 8; ++k) { Areg[k] = 0.f; hreg[k] = 0.f; }
    if (hd < NN) {
        #pragma unroll
        for (int k = 0; k < 8; ++k) {
            Areg[k] = Aw[hd * SSZ + hc * 8 + k];
            hreg[k] = state_init[hd * SSZ + hc * 8 + k];
        }
    }

    // biases, pads, feat
    if (tid < 128) { lb1[tid] = lift_b1[tid]; nb1[tid] = net_b1[tid]; }
    if (tid < 121) {
        lb2[tid] = lift_b2[tid]; nb2[tid] = net_b2[tid];
        f1b[tid] = fc1_b[tid];   fob[tid] = fcout_b[tid];
        t1[tid] = feat_in[tid];
    }
    if (tid < 64) { f2b[tid] = fc2_b[tid]; f3b[tid] = fc3_b[tid]; }
    if (tid >= 121 && tid < 128) { catP[tid] = 0.f; xtsP[tid] = 0.f; outvP[tid] = 0.f; t2[tid] = 0.f; }
    if (tid >= 249 && tid < 256) catP[tid] = 0.f;
    __syncthreads();

    // adapter: z = feat @ adapter_w + b  (fp32 streamed, once) -> t2
    matvec8<NN, NN, 0>(adapter_w, adapter_b, t1, t2, red, tid);

    // layernorm(t2) -> catP[0..121)
    {
        if (tid < 128) {
            const float v = (tid < NN) ? t2[tid] : 0.f;
            r128[tid] = v; q128[tid] = v * v;
        }
        __syncthreads();
        for (int s = 64; s > 0; s >>= 1) {
            if (tid < s) { r128[tid] += r128[tid + s]; q128[tid] += q128[tid + s]; }
            __syncthreads();
        }
        if (tid == 0) {
            const float mu = r128[0] / (float)NN;
            const float var = q128[0] / (float)NN - mu * mu;
            scal[0] = mu; scal[1] = 1.0f / sqrtf(var + 1e-5f);
        }
        __syncthreads();
        if (tid < NN) catP[tid] = (t2[tid] - scal[0]) * scal[1] * ln_g[tid] + ln_b[tid];
        __syncthreads();
    }

    // ev 0 = warmup (h only), ev 1..6 = steps
    for (int ev = 0; ev < 7; ++ev) {
        stream_mv<128, 1>(WL1g, lb1, catP, t1, red, tid);          // relu
        stream_mv<121, 2>(WL2g, lb2, t1, catP + 128, red, tid);    // tanh -> lifted

        // net1 from LDS: [128 pairs][128], in = catP[0..256)
        {
            const int s = tid >> 7, j = tid & 127;
            float acc = 0.f;
            #pragma unroll
            for (int p = 0; p < 16; ++p) {
                const h16x2 h = u2h(WN1[(s * 16 + p) * 128 + j]);
                const int r = s * 32 + 2 * p;
                acc += catP[r] * (float)h.x + catP[r + 1] * (float)h.y;
            }
            red[tid] = acc;
            __syncthreads();
            if (tid < 128) {
                float v = nb1[tid];
                #pragma unroll
                for (int c = 0; c < 8; ++c) v += red[tid + 128 * c];
                t2[tid] = fmaxf(v, 0.f);
            }
            __syncthreads();
        }

        stream_mv<121, 0>(WN2g, nb2, t2, xtsP, red, tid);          // xt

        // fused fc1/fc2/fc3 from LDS: [64 pairs][256], in = xtsP[0..128)
        {
            const int s = tid >> 8, j = tid & 255;
            float acc = 0.f;
            #pragma unroll
            for (int p = 0; p < 16; ++p) {
                const h16x2 h = u2h(WF[(s * 16 + p) * 256 + j]);
                const int r = s * 32 + 2 * p;
                acc += xtsP[r] * (float)h.x + xtsP[r + 1] * (float)h.y;
            }
            red[tid] = acc;
            __syncthreads();
            if (tid < 256) {
                const float val = red[tid] + red[tid + 256] + red[tid + 512] + red[tid + 768];
                if (tid < 121)
                    deltas[tid] = softplus_f(val + f1b[tid]);
                else if (tid >= 128 && tid < 192)
                    Bms[tid - 128] = val + f2b[tid - 128];
                else if (tid >= 192)
                    Cms[tid - 192] = val + f3b[tid - 192];
            }
            __syncthreads();
        }

        // h update + out[d] = sum_n Cm[n]*h_new[d,n]
        {
            float acc = 0.f;
            if (hd < NN) {
                const float dd = deltas[hd];
                const float coef = xtsP[hd] * dd;
                #pragma unroll
                for (int k = 0; k < 8; ++k) {
                    const float s = dd * Areg[k];
                    const float cel = s > 0.f ? s : expm1f(s);   // celu, alpha=1
                    const float dAv = expf(-cel);
                    const float hn = dAv * hreg[k] + coef * Bms[hc * 8 + k];
                    hreg[k] = hn;
                    acc += Cms[hc * 8 + k] * hn;
                }
            }
            red[tid] = acc;
            __syncthreads();
            if (tid < NN) {
                float s = 0.f;
                #pragma unroll
                for (int c = 0; c < 8; ++c) s += red[tid + 128 * c];
                outvP[tid] = s;
            }
            __syncthreads();
        }

        if (ev > 0) {
            stream_mv<121, 0>(WOg, fob, outvP, catP, red, tid);    // pred -> q
            if (tid < NN) pred_out[(ev - 1) * NN + tid] = catP[tid];
            __syncthreads();
        }
    }
}

// ---------------- kernel 3: broadcast preds to (steps,b,l,m) ----------------
__global__ __launch_bounds__(128) void bcast_kernel(
    const float* __restrict__ pred, float* __restrict__ out)
{
    const int row = blockIdx.x;
    const int s = row / BL;
    const int t = threadIdx.x;
    if (t < NN) out[row * NN + t] = pred[s * NN + t];
}

extern "C" void kernel_launch(void* const* d_in, const int* in_sizes, int n_in,
                              void* d_out, int out_size, void* d_ws, size_t ws_size,
                              hipStream_t stream)
{
    const float* x        = (const float*)d_in[0];
    const float* conv_w   = (const float*)d_in[3];
    const float* conv_b   = (const float*)d_in[4];
    const float* comp_w1  = (const float*)d_in[5];
    const float* comp_b1  = (const float*)d_in[6];
    const float* comp_w2  = (const float*)d_in[7];
    const float* comp_b2  = (const float*)d_in[8];
    const float* adapter_w= (const float*)d_in[9];
    const float* adapter_b= (const float*)d_in[10];
    const float* ln_g     = (const float*)d_in[11];
    const float* ln_b     = (const float*)d_in[12];
    const float* lift_w1  = (const float*)d_in[13];
    const float* lift_b1  = (const float*)d_in[14];
    const float* lift_w2  = (const float*)d_in[15];
    const float* lift_b2  = (const float*)d_in[16];
    const float* net_w1   = (const float*)d_in[17];
    const float* net_b1   = (const float*)d_in[18];
    const float* net_w2   = (const float*)d_in[19];
    const float* net_b2   = (const float*)d_in[20];
    const float* fc1_w    = (const float*)d_in[21];
    const float* fc1_b    = (const float*)d_in[22];
    const float* fc2_w    = (const float*)d_in[23];
    const float* fc2_b    = (const float*)d_in[24];
    const float* fc3_w    = (const float*)d_in[25];
    const float* fc3_b    = (const float*)d_in[26];
    const float* Aw       = (const float*)d_in[27];
    const float* state_in = (const float*)d_in[28];
    const float* fcout_w  = (const float*)d_in[29];
    const float* fcout_b  = (const float*)d_in[30];

    float* ws   = (float*)d_ws;
    float* feat = ws;          // 121 floats
    float* pred = ws + 128;    // 6*121 floats
    uint16_t* w16 = (uint16_t*)((char*)d_ws + 4096);
    const uint32_t* w32 = (const uint32_t*)w16;

    enc_kernel<<<NN, 256, 0, stream>>>(x, conv_w, conv_b, comp_w1, comp_b1,
                                       comp_w2, comp_b2, feat);
    prep_kernel<<<TOT_HALVES / 256, 256, 0, stream>>>(
        lift_w1, lift_w2, net_w1, net_w2, fc1_w, fc2_w, fc3_w, fcout_w, w16);
    mamba_kernel<<<1, NT, 0, stream>>>(adapter_w, adapter_b, ln_g, ln_b,
        lift_b1, lift_b2, net_b1, net_b2, fc1_b, fc2_b, fc3_b, fcout_b,
        Aw, state_in, w32, feat, pred);
    bcast_kernel<<<NSTEPS * BL, 128, 0, stream>>>(pred, (float*)d_out);
}

// Round 15
// 174.873 us; speedup vs baseline: 1.8691x; 1.0275x over previous
//
#include <hip/hip_runtime.h>
#include <hip/hip_bf16.h>
#include <math.h>

#define BATCH 128
#define LSEQ 24
#define NN 121      // nodes == d_model == out feature
#define SSZ 64      // state size
#define NSTEPS 6
#define BL 3072     // BATCH*LSEQ
#define NT 1024     // mamba block size

typedef _Float16 h16;
typedef _Float16 h16x2 __attribute__((ext_vector_type(2)));
typedef float    fv8  __attribute__((ext_vector_type(8)));

// ws packed fp16 weight region (u16 element offsets), base at byte 4096
#define OFF_WL1 0        // [64 pairs][128 cols]  lift_w1 (R=121,C=128)
#define OFF_WL2 16384    // [64][128]             lift_w2 (R=128,C=121)
#define OFF_WN2 32768    // [64][128]             net_w2  (R=128,C=121)
#define OFF_WO  49152    // [64][128]             fcout_w (R=121,C=121)
#define OFF_WN1 65536    // [128][128]            net_w1 remapped to 256 padded rows
#define OFF_WF  98304    // [64][256]             fused fc1/fc2/fc3 (121 rows)
#define TOT_HALVES 131072

__device__ __forceinline__ h16x2 u2h(uint32_t u) {
    union { uint32_t u; h16x2 h; } c; c.u = u; return c.h;
}
__device__ __forceinline__ uint16_t f2u16(float v) {
    union { h16 h; uint16_t u; } c; c.h = (h16)v; return c.u;
}

// ---------------- kernel 1: encoder -> feat[121] (unchanged, verified) ----------------
__global__ __launch_bounds__(256) void enc_kernel(
    const float* __restrict__ x, const float* __restrict__ conv_w,
    const float* __restrict__ conv_b, const float* __restrict__ comp_w1,
    const float* __restrict__ comp_b1, const float* __restrict__ comp_w2,
    const float* __restrict__ comp_b2, float* __restrict__ feat_out)
{
    const int n = blockIdx.x;
    const int tid = threadIdx.x;
    float acc[8] = {0.f,0.f,0.f,0.f,0.f,0.f,0.f,0.f};
    for (int i = tid; i < BL; i += 256) {
        const float xv = x[i * NN + n];
        const float4* w4 = reinterpret_cast<const float4*>(conv_w + i * 8);
        const float4 a = w4[0], b = w4[1];
        acc[0] += xv * a.x; acc[1] += xv * a.y; acc[2] += xv * a.z; acc[3] += xv * a.w;
        acc[4] += xv * b.x; acc[5] += xv * b.y; acc[6] += xv * b.z; acc[7] += xv * b.w;
    }
    __shared__ float red[256][9];
    __shared__ float hred[32];
    #pragma unroll
    for (int j = 0; j < 8; ++j) red[tid][j] = acc[j];
    __syncthreads();
    for (int s = 128; s > 0; s >>= 1) {
        if (tid < s) {
            #pragma unroll
            for (int j = 0; j < 8; ++j) red[tid][j] += red[tid + s][j];
        }
        __syncthreads();
    }
    if (tid < 32) {
        float g[8];
        #pragma unroll
        for (int j = 0; j < 8; ++j) g[j] = red[0][j] + conv_b[j];
        float hsum = comp_b1[tid];
        #pragma unroll
        for (int j = 0; j < 8; ++j)
            hsum += g[j] * (comp_w1[j * 32 + tid] + comp_w1[(j + 8) * 32 + tid]);
        const float hv = hsum > 0.f ? hsum : 0.01f * hsum;
        hred[tid] = hv * comp_w2[tid];
    }
    __syncthreads();
    if (tid == 0) {
        float f = comp_b2[0];
        #pragma unroll
        for (int m = 0; m < 32; ++m) f += hred[m];
        feat_out[n] = f;
    }
}

// ---------------- kernel 1b: pack all weights to fp16 row-pair layout in ws ----------
__global__ __launch_bounds__(256) void prep_kernel(
    const float* __restrict__ lift_w1, const float* __restrict__ lift_w2,
    const float* __restrict__ net_w1,  const float* __restrict__ net_w2,
    const float* __restrict__ fc1_w,   const float* __restrict__ fc2_w,
    const float* __restrict__ fc3_w,   const float* __restrict__ fcout_w,
    uint16_t* __restrict__ ws16)
{
    const int i = blockIdx.x * 256 + threadIdx.x;
    if (i >= TOT_HALVES) return;
    float v = 0.f;
    if (i < OFF_WL2) {                    // wl1: R=121, C=128, COLSP=128
        const int l = i, e = l & 1, j = (l >> 1) & 127, pp = l >> 8;
        const int rp = 2 * pp + e;
        if (rp < 121) v = lift_w1[rp * 128 + j];
    } else if (i < OFF_WN2) {             // wl2: R=128, C=121
        const int l = i - OFF_WL2, e = l & 1, j = (l >> 1) & 127, pp = l >> 8;
        const int rp = 2 * pp + e;
        if (j < 121 && rp < 128) v = lift_w2[rp * 121 + j];
    } else if (i < OFF_WO) {              // wn2: R=128, C=121
        const int l = i - OFF_WN2, e = l & 1, j = (l >> 1) & 127, pp = l >> 8;
        const int rp = 2 * pp + e;
        if (j < 121 && rp < 128) v = net_w2[rp * 121 + j];
    } else if (i < OFF_WN1) {             // wo: R=121, C=121
        const int l = i - OFF_WO, e = l & 1, j = (l >> 1) & 127, pp = l >> 8;
        const int rp = 2 * pp + e;
        if (j < 121 && rp < 121) v = fcout_w[rp * 121 + j];
    } else if (i < OFF_WF) {              // wn1: padded rows 0..255; 0..120=q, 128..248=lifted(-7)
        const int l = i - OFF_WN1, e = l & 1, j = (l >> 1) & 127, pp = l >> 8;
        const int rp = 2 * pp + e;
        const int o = rp < 121 ? rp : (rp >= 128 && rp < 249 ? rp - 7 : -1);
        if (o >= 0) v = net_w1[o * 128 + j];
    } else {                              // wf: fused fc1/fc2/fc3, rows 121 pad 128, COLSP=256
        const int l = i - OFF_WF, e = l & 1, j = (l >> 1) & 255, pp = l >> 9;
        const int rp = 2 * pp + e;
        if (rp < 121) {
            if (j < 121)                 v = fc1_w[rp * 121 + j];
            else if (j >= 128 && j < 192) v = fc2_w[rp * 64 + (j - 128)];
            else if (j >= 192)            v = fc3_w[rp * 64 + (j - 192)];
        }
    }
    ws16[i] = f2u16(v);
}

// ---------------- kernel 2: sequential mamba chain ----------------
__device__ __forceinline__ float softplus_f(float v) {
    return v > 20.f ? v : log1pf(expf(v));
}

// streaming fp32 matvec, 8 row-slices (used once, for adapter)
template<int ROWS, int COLS, int ACT>
__device__ __forceinline__ void matvec8(
    const float* __restrict__ W, const float* __restrict__ bias,
    const float* in, float* out, float* red, int tid)
{
    const int slice = tid >> 7;
    const int j = tid & 127;
    float a0 = 0.f;
    if (j < COLS) {
        const int r0 = (ROWS * slice) >> 3;
        const int r1 = (ROWS * (slice + 1)) >> 3;
        for (int i = r0; i < r1; ++i) a0 += in[i] * W[i * COLS + j];
    }
    red[tid] = a0;
    __syncthreads();
    if (tid < COLS) {
        float s = bias[tid];
        #pragma unroll
        for (int c = 0; c < 8; ++c) s += red[tid + 128 * c];
        if (ACT == 1) s = fmaxf(s, 0.f);
        else if (ACT == 2) s = tanhf(s);
        out[tid] = s;
    }
    __syncthreads();
}

// streamed fp16-pair matvec from ws: [64 pairs][128 cols], PADR=128
template<int COLS, int ACT>
__device__ __forceinline__ void stream_mv(
    const uint32_t* __restrict__ g, const float* __restrict__ biasLds,
    const float* in, float* out, float* red, int tid)
{
    const int s = tid >> 7, j = tid & 127;
    float acc = 0.f;
    #pragma unroll
    for (int p = 0; p < 8; ++p) {
        const h16x2 h = u2h(g[(s * 8 + p) * 128 + j]);
        const int r = s * 16 + 2 * p;
        acc += in[r] * (float)h.x + in[r + 1] * (float)h.y;
    }
    red[tid] = acc;
    __syncthreads();
    if (tid < COLS) {
        float v = biasLds[tid];
        #pragma unroll
        for (int c = 0; c < 8; ++c) v += red[tid + 128 * c];
        if (ACT == 1) v = fmaxf(v, 0.f);
        else if (ACT == 2) v = tanhf(v);
        out[tid] = v;
    }
    __syncthreads();
}

__global__ __launch_bounds__(NT) void mamba_kernel(
    const float* __restrict__ adapter_w, const float* __restrict__ adapter_b,
    const float* __restrict__ ln_g, const float* __restrict__ ln_b,
    const float* __restrict__ lift_b1, const float* __restrict__ lift_b2,
    const float* __restrict__ net_b1,  const float* __restrict__ net_b2,
    const float* __restrict__ fc1_b,   const float* __restrict__ fc2_b,
    const float* __restrict__ fc3_b,   const float* __restrict__ fcout_b,
    const float* __restrict__ Aw, const float* __restrict__ state_init,
    const uint32_t* __restrict__ wsp,   // packed fp16 pairs (u32)
    const float* __restrict__ feat_in, float* __restrict__ pred_out)
{
    __shared__ uint32_t WN1[16384];   // 64 KB: net_w1 [128 pairs][128]
    __shared__ uint32_t WF[16384];    // 64 KB: fused fc [64 pairs][256]
    __shared__ __align__(16) float catP[256];
    __shared__ __align__(16) float t1[128], t2[128], xtsP[128], outvP[128];
    __shared__ float deltas[128], Bms[64], Cms[64];
    __shared__ float red[NT];
    __shared__ float r128[128], q128[128];
    __shared__ float lb1[128], lb2[128], nb1[128], nb2[128];
    __shared__ float f1b[128], f2b[64], f3b[64], fob[128];
    __shared__ float scal[2];

    const int tid = threadIdx.x;
    const uint32_t* WL1g = wsp;                       // u32 offsets = u16/2
    const uint32_t* WL2g = wsp + 8192;
    const uint32_t* WN2g = wsp + 16384;
    const uint32_t* WOg  = wsp + 24576;

    // LDS weight staging
    #pragma unroll
    for (int k = 0; k < 16; ++k) {
        WN1[k * NT + tid] = wsp[32768 + k * NT + tid];
        WF [k * NT + tid] = wsp[49152 + k * NT + tid];
    }

    // per-thread A / h (8 n-values each)
    const int hc = tid >> 7, hd = tid & 127;
    fv8 Areg, hreg;
    #pragma unroll
    for (int k = 0; k < 8; ++k) { Areg[k] = 0.f; hreg[k] = 0.f; }
    if (hd < NN) {
        #pragma unroll
        for (int k = 0; k < 8; ++k) {
            Areg[k] = Aw[hd * SSZ + hc * 8 + k];
            hreg[k] = state_init[hd * SSZ + hc * 8 + k];
        }
    }

    // biases, pads, feat
    if (tid < 128) { lb1[tid] = lift_b1[tid]; nb1[tid] = net_b1[tid]; }
    if (tid < 121) {
        lb2[tid] = lift_b2[tid]; nb2[tid] = net_b2[tid];
        f1b[tid] = fc1_b[tid];   fob[tid] = fcout_b[tid];
        t1[tid] = feat_in[tid];
    }
    if (tid < 64) { f2b[tid] = fc2_b[tid]; f3b[tid] = fc3_b[tid]; }
    if (tid >= 121 && tid < 128) { catP[tid] = 0.f; xtsP[tid] = 0.f; outvP[tid] = 0.f; t2[tid] = 0.f; }
    if (tid >= 249 && tid < 256) catP[tid] = 0.f;
    __syncthreads();

    // adapter: z = feat @ adapter_w + b  (fp32 streamed, once) -> t2
    matvec8<NN, NN, 0>(adapter_w, adapter_b, t1, t2, red, tid);

    // layernorm(t2) -> catP[0..121)
    {
        if (tid < 128) {
            const float v = (tid < NN) ? t2[tid] : 0.f;
            r128[tid] = v; q128[tid] = v * v;
        }
        __syncthreads();
        for (int s = 64; s > 0; s >>= 1) {
            if (tid < s) { r128[tid] += r128[tid + s]; q128[tid] += q128[tid + s]; }
            __syncthreads();
        }
        if (tid == 0) {
            const float mu = r128[0] / (float)NN;
            const float var = q128[0] / (float)NN - mu * mu;
            scal[0] = mu; scal[1] = 1.0f / sqrtf(var + 1e-5f);
        }
        __syncthreads();
        if (tid < NN) catP[tid] = (t2[tid] - scal[0]) * scal[1] * ln_g[tid] + ln_b[tid];
        __syncthreads();
    }

    // ev 0 = warmup (h only), ev 1..6 = steps
    for (int ev = 0; ev < 7; ++ev) {
        stream_mv<128, 1>(WL1g, lb1, catP, t1, red, tid);          // relu
        stream_mv<121, 2>(WL2g, lb2, t1, catP + 128, red, tid);    // tanh -> lifted

        // net1 from LDS: [128 pairs][128], in = catP[0..256)
        {
            const int s = tid >> 7, j = tid & 127;
            float acc = 0.f;
            #pragma unroll
            for (int p = 0; p < 16; ++p) {
                const h16x2 h = u2h(WN1[(s * 16 + p) * 128 + j]);
                const int r = s * 32 + 2 * p;
                acc += catP[r] * (float)h.x + catP[r + 1] * (float)h.y;
            }
            red[tid] = acc;
            __syncthreads();
            if (tid < 128) {
                float v = nb1[tid];
                #pragma unroll
                for (int c = 0; c < 8; ++c) v += red[tid + 128 * c];
                t2[tid] = fmaxf(v, 0.f);
            }
            __syncthreads();
        }

        stream_mv<121, 0>(WN2g, nb2, t2, xtsP, red, tid);          // xt

        // fused fc1/fc2/fc3 from LDS: [64 pairs][256], in = xtsP[0..128)
        {
            const int s = tid >> 8, j = tid & 255;
            float acc = 0.f;
            #pragma unroll
            for (int p = 0; p < 16; ++p) {
                const h16x2 h = u2h(WF[(s * 16 + p) * 256 + j]);
                const int r = s * 32 + 2 * p;
                acc += xtsP[r] * (float)h.x + xtsP[r + 1] * (float)h.y;
            }
            red[tid] = acc;
            __syncthreads();
            if (tid < 256) {
                const float val = red[tid] + red[tid + 256] + red[tid + 512] + red[tid + 768];
                if (tid < 121)
                    deltas[tid] = softplus_f(val + f1b[tid]);
                else if (tid >= 128 && tid < 192)
                    Bms[tid - 128] = val + f2b[tid - 128];
                else if (tid >= 192)
                    Cms[tid - 192] = val + f3b[tid - 192];
            }
            __syncthreads();
        }

        // h update + out[d] = sum_n Cm[n]*h_new[d,n]
        {
            float acc = 0.f;
            if (hd < NN) {
                const float dd = deltas[hd];
                const float coef = xtsP[hd] * dd;
                #pragma unroll
                for (int k = 0; k < 8; ++k) {
                    const float s = dd * Areg[k];
                    const float cel = s > 0.f ? s : expm1f(s);   // celu, alpha=1
                    const float dAv = expf(-cel);
                    const float hn = dAv * hreg[k] + coef * Bms[hc * 8 + k];
                    hreg[k] = hn;
                    acc += Cms[hc * 8 + k] * hn;
                }
            }
            red[tid] = acc;
            __syncthreads();
            if (tid < NN) {
                float s = 0.f;
                #pragma unroll
                for (int c = 0; c < 8; ++c) s += red[tid + 128 * c];
                outvP[tid] = s;
            }
            __syncthreads();
        }

        if (ev > 0) {
            stream_mv<121, 0>(WOg, fob, outvP, catP, red, tid);    // pred -> q
            if (tid < NN) pred_out[(ev - 1) * NN + tid] = catP[tid];
            __syncthreads();
        }
    }
}

// ---------------- kernel 3: broadcast preds (144 fat blocks, 62 KB each) ----------------
// block = s*24 + chunk; writes rows [s*3072+chunk*128, +128) x 121 floats, contiguous.
__global__ __launch_bounds__(256) void bcast_kernel(
    const float* __restrict__ pred, float* __restrict__ out)
{
    __shared__ float p[128];
    const int blk = blockIdx.x;
    const int s = blk / 24, chunk = blk - s * 24;
    const int t = threadIdx.x;
    if (t < NN) p[t] = pred[s * NN + t];
    __syncthreads();
    float* dst = out + ((long)s * BL + (long)chunk * 128) * NN;
    for (int idx = t; idx < 128 * NN; idx += 256)
        dst[idx] = p[idx % NN];
}

extern "C" void kernel_launch(void* const* d_in, const int* in_sizes, int n_in,
                              void* d_out, int out_size, void* d_ws, size_t ws_size,
                              hipStream_t stream)
{
    const float* x        = (const float*)d_in[0];
    const float* conv_w   = (const float*)d_in[3];
    const float* conv_b   = (const float*)d_in[4];
    const float* comp_w1  = (const float*)d_in[5];
    const float* comp_b1  = (const float*)d_in[6];
    const float* comp_w2  = (const float*)d_in[7];
    const float* comp_b2  = (const float*)d_in[8];
    const float* adapter_w= (const float*)d_in[9];
    const float* adapter_b= (const float*)d_in[10];
    const float* ln_g     = (const float*)d_in[11];
    const float* ln_b     = (const float*)d_in[12];
    const float* lift_w1  = (const float*)d_in[13];
    const float* lift_b1  = (const float*)d_in[14];
    const float* lift_w2  = (const float*)d_in[15];
    const float* lift_b2  = (const float*)d_in[16];
    const float* net_w1   = (const float*)d_in[17];
    const float* net_b1   = (const float*)d_in[18];
    const float* net_w2   = (const float*)d_in[19];
    const float* net_b2   = (const float*)d_in[20];
    const float* fc1_w    = (const float*)d_in[21];
    const float* fc1_b    = (const float*)d_in[22];
    const float* fc2_w    = (const float*)d_in[23];
    const float* fc2_b    = (const float*)d_in[24];
    const float* fc3_w    = (const float*)d_in[25];
    const float* fc3_b    = (const float*)d_in[26];
    const float* Aw       = (const float*)d_in[27];
    const float* state_in = (const float*)d_in[28];
    const float* fcout_w  = (const float*)d_in[29];
    const float* fcout_b  = (const float*)d_in[30];

    float* ws   = (float*)d_ws;
    float* feat = ws;          // 121 floats
    float* pred = ws + 128;    // 6*121 floats
    uint16_t* w16 = (uint16_t*)((char*)d_ws + 4096);
    const uint32_t* w32 = (const uint32_t*)w16;

    enc_kernel<<<NN, 256, 0, stream>>>(x, conv_w, conv_b, comp_w1, comp_b1,
                                       comp_w2, comp_b2, feat);
    prep_kernel<<<TOT_HALVES / 256, 256, 0, stream>>>(
        lift_w1, lift_w2, net_w1, net_w2, fc1_w, fc2_w, fc3_w, fcout_w, w16);
    mamba_kernel<<<1, NT, 0, stream>>>(adapter_w, adapter_b, ln_g, ln_b,
        lift_b1, lift_b2, net_b1, net_b2, fc1_b, fc2_b, fc3_b, fcout_b,
        Aw, state_in, w32, feat, pred);
    bcast_kernel<<<NSTEPS * 24, 256, 0, stream>>>(pred, (float*)d_out);
}